// Round 10
// baseline (517.335 us; speedup 1.0000x reference)
//
#include <hip/hip_runtime.h>
#include <hip/hip_bf16.h>
#include <math.h>

#define DIMD 512
#define NLAYER 4
#define PP 8
#define BBATCH 4
#define LBYTES 8192
#define LPATCH 1024
#define MROWS (BBATCH * LPATCH)   // 4096

#define NCHUNK 64
#define CLEN   16
#define QGS    (4 * DIMD)   // 2048

typedef __bf16 bf16x8 __attribute__((ext_vector_type(8)));
typedef float f32x4 __attribute__((ext_vector_type(4)));
typedef unsigned short u16x4 __attribute__((ext_vector_type(4)));
typedef unsigned short u16x8 __attribute__((ext_vector_type(8)));

__device__ __forceinline__ unsigned short f2bf(float f) {
    union { float f; unsigned u; } v; v.f = f;
    unsigned r = v.u + 0x7FFFu + ((v.u >> 16) & 1u);   // RNE
    return (unsigned short)(r >> 16);
}
__device__ __forceinline__ float bf2f(unsigned short u) {
    union { unsigned u; float f; } v; v.u = ((unsigned)u) << 16;
    return v.f;
}

__device__ __forceinline__ void glds16(const unsigned short* g, unsigned short* l) {
    __builtin_amdgcn_global_load_lds((__attribute__((address_space(1))) void*)g,
                                     (__attribute__((address_space(3))) void*)l,
                                     16, 0, 0);
}

// =======================================================================
// bf16 MFMA GEMM (NT): C[M,N] = act(A[M,K] @ Bt[N,K]^T + bias) (+res)
// (R5-proven structure — do not touch)
// =======================================================================
template<int TM, int ACT, bool BIAS, bool RES, bool OBF>
__global__ __launch_bounds__(256)
void mfma_gemm(const unsigned short* __restrict__ A, int lda, long aZ,
               const unsigned short* __restrict__ Bt, int ldb, long bZ,
               const float* __restrict__ bias,
               const float* __restrict__ res, int ldr,
               void* __restrict__ Cv, int ldc, long cZ, int K)
{
    constexpr int M_REP = TM / 32;
    __shared__ unsigned short As[TM * 32];
    __shared__ unsigned short Bs[128 * 32];

    const int tid = threadIdx.x;
    const int w = tid >> 6, l = tid & 63;
    const int row0 = blockIdx.x * TM;
    const int col0 = blockIdx.y * 128;
    A  += (size_t)blockIdx.z * aZ;
    Bt += (size_t)blockIdx.z * bZ;
    unsigned short* Cb = (unsigned short*)Cv + (size_t)blockIdx.z * cZ;
    float*          Cf = (float*)Cv          + (size_t)blockIdx.z * cZ;

    const int cA = w * 64 + l;
    const unsigned short* gA0 = A + (size_t)(row0 + (cA >> 2)) * lda + (cA & 3) * 8;
    const unsigned short* gB0 = Bt + (size_t)(col0 + (cA >> 2)) * ldb + (cA & 3) * 8;
    const unsigned short* gB1 = Bt + (size_t)(col0 + 64 + (cA >> 2)) * ldb + (cA & 3) * 8;
    unsigned short* lA0 = &As[w * 512];
    unsigned short* lB0 = &Bs[w * 512];
    unsigned short* lB1 = &Bs[2048 + w * 512];
    const unsigned short* gA1 = nullptr;
    unsigned short* lA1 = nullptr;
    if constexpr (TM == 128) {
        gA1 = A + (size_t)(row0 + 64 + (cA >> 2)) * lda + (cA & 3) * 8;
        lA1 = &As[2048 + w * 512];
    }

    const int wr = (w >> 1) * (TM / 2);
    const int wc = (w & 1) * 64;
    const int lr = l & 15, lk = (l >> 4) * 8;
    const int aBase = (wr + lr) * 32 + lk;
    const int bBase = (wc + lr) * 32 + lk;

    f32x4 acc[M_REP][4] = {};

    for (int k0 = 0; k0 < K; k0 += 32) {
        glds16(gA0, lA0);  gA0 += 32;
        if constexpr (TM == 128) { glds16(gA1, lA1); gA1 += 32; }
        glds16(gB0, lB0);  gB0 += 32;
        glds16(gB1, lB1);  gB1 += 32;
        __syncthreads();
        bf16x8 af[M_REP], bfr[4];
        #pragma unroll
        for (int m = 0; m < M_REP; m++)
            af[m] = *reinterpret_cast<const bf16x8*>(&As[aBase + m * 512]);
        #pragma unroll
        for (int n = 0; n < 4; n++)
            bfr[n] = *reinterpret_cast<const bf16x8*>(&Bs[bBase + n * 512]);
        #pragma unroll
        for (int m = 0; m < M_REP; m++)
            #pragma unroll
            for (int n = 0; n < 4; n++)
                acc[m][n] = __builtin_amdgcn_mfma_f32_16x16x32_bf16(
                    af[m], bfr[n], acc[m][n], 0, 0, 0);
        __syncthreads();
    }

    const int r0 = row0 + wr + (l >> 4) * 4;
    const int c0 = col0 + wc + lr;
    float bv[4] = {0.f, 0.f, 0.f, 0.f};
    if (BIAS) {
        #pragma unroll
        for (int n = 0; n < 4; n++) bv[n] = bias[c0 + n * 16];
    }
    #pragma unroll
    for (int m = 0; m < M_REP; m++) {
        #pragma unroll
        for (int j = 0; j < 4; j++) {
            const int row = r0 + m * 16 + j;
            #pragma unroll
            for (int n = 0; n < 4; n++) {
                float v = acc[m][n][j];
                if (BIAS) v += bv[n];
                if (ACT == 1) v = tanhf(v);
                if (ACT == 2) v = 0.5f * v * (1.f + erff(v * 0.70710678118f));
                if (RES) v += res[(size_t)row * ldr + c0 + n * 16];
                if (OBF) Cb[(size_t)row * ldc + c0 + n * 16] = f2bf(v);
                else     Cf[(size_t)row * ldc + c0 + n * 16] = v;
            }
        }
    }
}

// ======================= megapack: all weight preprocessing =======================
// 64x64 tiles, float2 global reads (8B/lane), [64][66] LDS.
__device__ __forceinline__ void packT64(float* sm, const float* __restrict__ in,
                                        unsigned short* __restrict__ out,
                                        int K, int N, int bk, int bn)
{
    float (*t)[66] = (float(*)[66])sm;
    const int k0 = bk * 64, n0 = bn * 64;
    const int r = threadIdx.x >> 5;
    const int c2 = (threadIdx.x & 31) * 2;
    #pragma unroll
    for (int i = 0; i < 8; i++) {
        float2 v = *(const float2*)(in + (size_t)(k0 + r + i * 8) * N + n0 + c2);
        *(float2*)&t[r + i * 8][c2] = v;
    }
    __syncthreads();
    const int tx = threadIdx.x & 63, ty = threadIdx.x >> 6;
    #pragma unroll
    for (int i = 0; i < 16; i++)
        out[(size_t)(n0 + ty + i * 4) * K + k0 + tx] = f2bf(t[tx][ty + i * 4]);
}

__device__ __forceinline__ void cast_body(const float* __restrict__ in,
                                          unsigned short* __restrict__ out, int blk)
{
    const long i = ((long)blk * 256 + threadIdx.x) * 8;
    float4 a = *(const float4*)(in + i);
    float4 b = *(const float4*)(in + i + 4);
    u16x8 o;
    o[0] = f2bf(a.x); o[1] = f2bf(a.y); o[2] = f2bf(a.z); o[3] = f2bf(a.w);
    o[4] = f2bf(b.x); o[5] = f2bf(b.y); o[6] = f2bf(b.z); o[7] = f2bf(b.w);
    *reinterpret_cast<u16x8*>(out + i) = o;
}

__global__ __launch_bounds__(256)
void megapack(const float* __restrict__ qkv_w, const float* __restrict__ gate_w,
              const float* __restrict__ mlp_w1, const float* __restrict__ mlp_w2,
              const float* __restrict__ hash_proj, const float* __restrict__ head_w,
              const float* __restrict__ enc_w, const float* __restrict__ dec_w,
              const float* __restrict__ byte_emb,
              const float* __restrict__ qkv_b, const float* __restrict__ gate_b,
              const float* __restrict__ dec_b, const float* __restrict__ head_b,
              unsigned short* __restrict__ wcat, unsigned short* __restrict__ w1T,
              unsigned short* __restrict__ w2T, unsigned short* __restrict__ whashT,
              unsigned short* __restrict__ hwT, unsigned short* __restrict__ encT,
              unsigned short* __restrict__ decb, unsigned short* __restrict__ embB,
              float* __restrict__ cbias, float* __restrict__ fb)
{
    __shared__ float sm[64 * 66];
    int id = blockIdx.x;
    if (id < 768) {                  // qkv_w: z4, [512][1536] (8x24 tiles)
        int z = id / 192, r = id % 192;
        packT64(sm, qkv_w + (size_t)z * 512 * 1536, wcat + (size_t)z * 2048 * 512,
                512, 1536, r % 8, r / 8);
    } else if (id < 1024) {          // gate_w: z4, [512][512] (8x8)
        id -= 768; int z = id / 64, r = id % 64;
        packT64(sm, gate_w + (size_t)z * 512 * 512,
                wcat + (size_t)z * 2048 * 512 + (size_t)1536 * 512,
                512, 512, r % 8, r / 8);
    } else if (id < 2048) {          // mlp_w1: z4, [512][2048] (8x32)
        id -= 1024; int z = id / 256, r = id % 256;
        packT64(sm, mlp_w1 + (size_t)z * 512 * 2048, w1T + (size_t)z * 2048 * 512,
                512, 2048, r % 8, r / 8);
    } else if (id < 3072) {          // mlp_w2: z4, [2048][512] (32x8)
        id -= 2048; int z = id / 256, r = id % 256;
        packT64(sm, mlp_w2 + (size_t)z * 2048 * 512, w2T + (size_t)z * 512 * 2048,
                2048, 512, r & 31, r >> 5);
    } else if (id < 3136) {          // hash_proj (8x8)
        id -= 3072;
        packT64(sm, hash_proj, whashT, 512, 512, id % 8, id / 8);
    } else if (id < 3168) {          // head_w: [512][256] (8x4)
        id -= 3136;
        packT64(sm, head_w, hwT, 512, 256, id % 8, id / 8);
    } else if (id < 3680) {          // enc_w: z8, [512][512] (8x8)
        id -= 3168; int z = id / 64, r = id % 64;
        packT64(sm, enc_w + (size_t)z * 512 * 512, encT + (size_t)z * 512 * 512,
                512, 512, r % 8, r / 8);
    } else if (id < 4704) {          // dec_w cast
        cast_body(dec_w, decb, id - 3680);
    } else if (id < 4768) {          // byte_emb cast
        cast_body(byte_emb, embB, id - 4704);
    } else if (id < 4800) {          // catbias
        id -= 4768;
        const int i = id >> 3;
        const int n = (id & 7) * 256 + threadIdx.x;
        cbias[i * 2048 + n] = (n < 1536) ? qkv_b[i * 1536 + n] : gate_b[i * 512 + n - 1536];
    } else {                         // fused decoder+head bias (1 block)
        const int o = threadIdx.x;
        float s = head_b[o];
        for (int d = 0; d < DIMD; d++) s = fmaf(dec_b[d], head_w[d * 256 + o], s);
        #pragma unroll
        for (int p = 0; p < PP; p++) fb[p * 256 + o] = s;
    }
}

// ---- LayerNorm (ln1): one wave per row, bf16 out ----
__global__ __launch_bounds__(256)
void ln_kernel(const float* __restrict__ x, const float* __restrict__ g,
               const float* __restrict__ b, unsigned short* __restrict__ h)
{
    const int row = blockIdx.x * 4 + (threadIdx.x >> 6);
    const int lane = threadIdx.x & 63;
    const float* xr = x + (long)row * DIMD;
    float4 v0 = *(const float4*)(xr + lane * 8);
    float4 v1 = *(const float4*)(xr + lane * 8 + 4);
    float xv[8] = {v0.x, v0.y, v0.z, v0.w, v1.x, v1.y, v1.z, v1.w};
    float s = 0.f, q = 0.f;
    #pragma unroll
    for (int j = 0; j < 8; j++) { s += xv[j]; q += xv[j] * xv[j]; }
    #pragma unroll
    for (int off = 1; off < 64; off <<= 1) {
        s += __shfl_xor(s, off);
        q += __shfl_xor(q, off);
    }
    const float mean = s * (1.f / DIMD);
    const float var  = q * (1.f / DIMD) - mean * mean;
    const float rstd = rsqrtf(var + 1e-5f);
    float4 g0 = *(const float4*)(g + lane * 8);
    float4 g1 = *(const float4*)(g + lane * 8 + 4);
    float4 b0 = *(const float4*)(b + lane * 8);
    float4 b1 = *(const float4*)(b + lane * 8 + 4);
    float gv[8] = {g0.x, g0.y, g0.z, g0.w, g1.x, g1.y, g1.z, g1.w};
    float bb[8] = {b0.x, b0.y, b0.z, b0.w, b1.x, b1.y, b1.z, b1.w};
    u16x8 o;
    #pragma unroll
    for (int j = 0; j < 8; j++) o[j] = f2bf((xv[j] - mean) * rstd * gv[j] + bb[j]);
    *reinterpret_cast<u16x8*>(h + (long)row * DIMD + lane * 8) = o;
}

// ---- fused embed+encode ----
__global__ __launch_bounds__(128)
void embed_kernel(const int* __restrict__ bytes, const float* __restrict__ E,
                  const float* __restrict__ enc_b, float* __restrict__ x0,
                  unsigned short* __restrict__ x0b)
{
    const int patch = blockIdx.x;
    __shared__ int by[PP];
    if (threadIdx.x < PP) by[threadIdx.x] = bytes[patch * PP + threadIdx.x];
    __syncthreads();
    const int o = threadIdx.x * 4;
    float4 acc = *(const float4*)(enc_b + o);
    #pragma unroll
    for (int p = 0; p < PP; p++) {
        float4 e = *(const float4*)(E + ((long)(p * 256 + by[p])) * DIMD + o);
        acc.x += e.x; acc.y += e.y; acc.z += e.z; acc.w += e.w;
    }
    *(float4*)(x0 + (long)patch * DIMD + o) = acc;
    u16x4 ob; ob[0] = f2bf(acc.x); ob[1] = f2bf(acc.y);
    ob[2] = f2bf(acc.z); ob[3] = f2bf(acc.w);
    *reinterpret_cast<u16x4*>(x0b + (long)patch * DIMD + o) = ob;
}

// ---- scan partial sums: 256 thr, 2 dims/thread, ushort2 loads ----
__global__ __launch_bounds__(256)
void scan_partial(const unsigned short* __restrict__ qg, float* __restrict__ S)
{
    const int b = blockIdx.x >> 6, c = blockIdx.x & 63, d2 = threadIdx.x * 2;
    const unsigned short* base = qg + (size_t)(b * LPATCH + c * CLEN) * QGS;
    float s0 = 0.f, s1 = 0.f;
    for (int l = 0; l < CLEN; l++) {
        ushort2 kk = *(const ushort2*)(base + l * QGS + DIMD + d2);
        ushort2 vv = *(const ushort2*)(base + l * QGS + 2 * DIMD + d2);
        s0 = fmaf(bf2f(kk.x), bf2f(vv.x), s0);
        s1 = fmaf(bf2f(kk.y), bf2f(vv.y), s1);
    }
    *(float2*)(S + (size_t)(b * NCHUNK + c) * DIMD + d2) = make_float2(s0, s1);
}

// ---- fused own-prefix + scan apply + residual + LN2 (barrier-free) ----
// 512 thr = 8 waves; wave w owns rows [2w, 2w+2) of its 16-row chunk.
// S holds RAW chunk sums; each block sums chunks 0..c-1 itself (independent
// L2-hit loads, same order as the old scan_prefix → bit-identical). Then
// wave-local catch-up over preceding rows, apply, and in-wave LN2.
__global__ __launch_bounds__(512)
void scan_apply_ln(const unsigned short* __restrict__ qg,
                   const float* __restrict__ S, float* __restrict__ x,
                   const float* __restrict__ lg, const float* __restrict__ lb,
                   unsigned short* __restrict__ h)
{
    const int b = blockIdx.x >> 6, c = blockIdx.x & 63;
    const int w = threadIdx.x >> 6, lane = threadIdx.x & 63;
    const int d0 = lane * 8;

    float kv[8] = {0.f, 0.f, 0.f, 0.f, 0.f, 0.f, 0.f, 0.f};
    const float* Sb = S + (size_t)b * NCHUNK * DIMD + d0;
    for (int j = 0; j < c; j++) {
        float4 a = *(const float4*)(Sb + (size_t)j * DIMD);
        float4 bq = *(const float4*)(Sb + (size_t)j * DIMD + 4);
        kv[0] += a.x; kv[1] += a.y; kv[2] += a.z; kv[3] += a.w;
        kv[4] += bq.x; kv[5] += bq.y; kv[6] += bq.z; kv[7] += bq.w;
    }

    const int row0 = b * LPATCH + c * CLEN;
    for (int l = 0; l < 2 * w; l++) {
        const unsigned short* qb = qg + (size_t)(row0 + l) * QGS;
        u16x8 kk = *reinterpret_cast<const u16x8*>(qb + DIMD + d0);
        u16x8 vv = *reinterpret_cast<const u16x8*>(qb + 2 * DIMD + d0);
        #pragma unroll
        for (int j = 0; j < 8; j++) kv[j] = fmaf(bf2f(kk[j]), bf2f(vv[j]), kv[j]);
    }

    float gv[8], bv[8];
    {
        float4 g0 = *(const float4*)(lg + d0);
        float4 g1 = *(const float4*)(lg + d0 + 4);
        float4 b0 = *(const float4*)(lb + d0);
        float4 b1 = *(const float4*)(lb + d0 + 4);
        gv[0] = g0.x; gv[1] = g0.y; gv[2] = g0.z; gv[3] = g0.w;
        gv[4] = g1.x; gv[5] = g1.y; gv[6] = g1.z; gv[7] = g1.w;
        bv[0] = b0.x; bv[1] = b0.y; bv[2] = b0.z; bv[3] = b0.w;
        bv[4] = b1.x; bv[5] = b1.y; bv[6] = b1.z; bv[7] = b1.w;
    }

    for (int l = 2 * w; l < 2 * w + 2; l++) {
        const unsigned short* qb = qg + (size_t)(row0 + l) * QGS;
        u16x8 qq = *reinterpret_cast<const u16x8*>(qb + d0);
        u16x8 kk = *reinterpret_cast<const u16x8*>(qb + DIMD + d0);
        u16x8 vv = *reinterpret_cast<const u16x8*>(qb + 2 * DIMD + d0);
        u16x8 gg = *reinterpret_cast<const u16x8*>(qb + 3 * DIMD + d0);
        float* xr = x + (size_t)(row0 + l) * DIMD + d0;
        float4 xv0 = *(const float4*)xr;
        float4 xv1 = *(const float4*)(xr + 4);
        float xold[8] = {xv0.x, xv0.y, xv0.z, xv0.w, xv1.x, xv1.y, xv1.z, xv1.w};
        float xn[8];
        float s = 0.f, qs = 0.f;
        #pragma unroll
        for (int j = 0; j < 8; j++) {
            kv[j] = fmaf(bf2f(kk[j]), bf2f(vv[j]), kv[j]);
            const float sg = 1.f / (1.f + expf(-bf2f(gg[j])));
            const float nv = xold[j] + bf2f(qq[j]) * kv[j] * sg;
            xn[j] = nv; s += nv; qs += nv * nv;
        }
        *(float4*)xr       = make_float4(xn[0], xn[1], xn[2], xn[3]);
        *(float4*)(xr + 4) = make_float4(xn[4], xn[5], xn[6], xn[7]);
        #pragma unroll
        for (int off = 1; off < 64; off <<= 1) {
            s += __shfl_xor(s, off);
            qs += __shfl_xor(qs, off);
        }
        const float mean = s * (1.f / DIMD);
        const float var  = qs * (1.f / DIMD) - mean * mean;
        const float rstd = rsqrtf(var + 1e-5f);
        u16x8 ho;
        #pragma unroll
        for (int j = 0; j < 8; j++) ho[j] = f2bf((xn[j] - mean) * rstd * gv[j] + bv[j]);
        *reinterpret_cast<u16x8*>(h + (size_t)(row0 + l) * DIMD + d0) = ho;
    }
}

extern "C" void kernel_launch(void* const* d_in, const int* in_sizes, int n_in,
                              void* d_out, int out_size, void* d_ws, size_t ws_size,
                              hipStream_t stream)
{
    (void)in_sizes; (void)n_in; (void)out_size; (void)ws_size;

    const int*   bytes_in  = (const int*)d_in[0];
    const float* byte_emb  = (const float*)d_in[1];
    const float* enc_w     = (const float*)d_in[2];
    const float* enc_b     = (const float*)d_in[3];
    const float* hash_proj = (const float*)d_in[4];
    const float* qkv_w     = (const float*)d_in[5];
    const float* qkv_b     = (const float*)d_in[6];
    const float* gate_w    = (const float*)d_in[7];
    const float* gate_b    = (const float*)d_in[8];
    const float* ln1_g     = (const float*)d_in[9];
    const float* ln1_b     = (const float*)d_in[10];
    const float* mlp_w1    = (const float*)d_in[11];
    const float* mlp_b1    = (const float*)d_in[12];
    const float* mlp_w2    = (const float*)d_in[13];
    const float* mlp_b2    = (const float*)d_in[14];
    const float* ln2_g     = (const float*)d_in[15];
    const float* ln2_b     = (const float*)d_in[16];
    const float* dec_w     = (const float*)d_in[17];
    const float* dec_b     = (const float*)d_in[18];
    const float* head_w    = (const float*)d_in[19];
    const float* head_b    = (const float*)d_in[20];
    float* out = (float*)d_out;

    // ---- workspace layout ----
    char* ws = (char*)d_ws;
    size_t o = 0;
    auto alloc = [&](size_t bytes) { char* p = ws + o; o += (bytes + 255) & ~(size_t)255; return p; };
    unsigned short* wcat   = (unsigned short*)alloc((size_t)4 * 2048 * 512 * 2);
    unsigned short* w1T    = (unsigned short*)alloc((size_t)4 * 2048 * 512 * 2);
    unsigned short* w2T    = (unsigned short*)alloc((size_t)4 * 512 * 2048 * 2);
    unsigned short* whashT = (unsigned short*)alloc((size_t)512 * 512 * 2);
    unsigned short* wWfT   = (unsigned short*)alloc((size_t)2048 * 512 * 2);
    unsigned short* encT   = (unsigned short*)alloc((size_t)8 * 512 * 512 * 2);
    unsigned short* hwT    = (unsigned short*)alloc((size_t)256 * 512 * 2);
    unsigned short* decb   = (unsigned short*)alloc((size_t)512 * 8 * 512 * 2);
    unsigned short* embB   = (unsigned short*)alloc((size_t)256 * 512 * 2);
    float* cbias           = (float*)alloc((size_t)4 * 2048 * 4);
    float* fb              = (float*)alloc(2048 * 4);
    float* E               = (float*)alloc((size_t)8 * 256 * 512 * 4);
    float* x               = (float*)alloc((size_t)MROWS * DIMD * 4);
    float* x0              = (float*)alloc((size_t)MROWS * DIMD * 4);
    unsigned short* x0b    = (unsigned short*)alloc((size_t)MROWS * DIMD * 2);
    unsigned short* h      = (unsigned short*)alloc((size_t)MROWS * DIMD * 2);
    unsigned short* xb     = (unsigned short*)alloc((size_t)MROWS * DIMD * 2);
    float* S               = (float*)alloc((size_t)BBATCH * NCHUNK * DIMD * 4);
    unsigned short* qg     = (unsigned short*)alloc((size_t)MROWS * 2048 * 2);
    unsigned short* hid    = (unsigned short*)alloc((size_t)MROWS * 2048 * 2);

    // ---- 1. all weight preprocessing (incl. fused bias) in one launch ----
    megapack<<<dim3(4801), 256, 0, stream>>>(
        qkv_w, gate_w, mlp_w1, mlp_w2, hash_proj, head_w, enc_w, dec_w, byte_emb,
        qkv_b, gate_b, dec_b, head_b,
        wcat, w1T, w2T, whashT, hwT, encT, decb, embB, cbias, fb);

    // ---- 2. WfT[p*256+o][d] = sum_c head_wT[o][c] * dec_w[d][p][c] ----
    mfma_gemm<64, 0, false, false, true><<<dim3(4, 4, 8), 256, 0, stream>>>(
        hwT, 512, 0L, decb, PP * 512, 512L,
        nullptr, nullptr, 0, wWfT, 512, (long)256 * 512, 512);

    // ---- 3. E[p] = byte_emb @ enc_w[p] ----
    mfma_gemm<64, 0, false, false, false><<<dim3(4, 4, 8), 256, 0, stream>>>(
        embB, 512, 0L, encT, 512, (long)512 * 512,
        nullptr, nullptr, 0, E, 512, (long)256 * 512, 512);

    embed_kernel<<<dim3(MROWS), dim3(128), 0, stream>>>(bytes_in, E, enc_b, x0, x0b);

    // ---- 4. x = x0 + tanh(x0 @ hash_proj) ----
    mfma_gemm<64, 1, false, true, false><<<dim3(MROWS / 64, 4, 1), 256, 0, stream>>>(
        x0b, DIMD, 0L, whashT, DIMD, 0L, nullptr, x0, DIMD, x, DIMD, 0L, DIMD);

    for (int i = 0; i < NLAYER; i++) {
        ln_kernel<<<dim3(MROWS / 4), 256, 0, stream>>>(x, ln1_g + i * DIMD, ln1_b + i * DIMD, h);
        mfma_gemm<128, 0, true, false, true><<<dim3(MROWS / 128, 16, 1), 256, 0, stream>>>(
            h, DIMD, 0L, wcat + (size_t)i * 2048 * 512, DIMD, 0L,
            cbias + (size_t)i * 2048, nullptr, 0, qg, 2048, 0L, DIMD);
        scan_partial<<<dim3(BBATCH * NCHUNK), 256, 0, stream>>>(qg, S);
        scan_apply_ln<<<dim3(BBATCH * NCHUNK), dim3(512), 0, stream>>>(
            qg, S, x, ln2_g + i * DIMD, ln2_b + i * DIMD, h);
        mfma_gemm<128, 2, true, false, true><<<dim3(MROWS / 128, 16, 1), 256, 0, stream>>>(
            h, DIMD, 0L, w1T + (size_t)i * 2048 * 512, DIMD, 0L,
            mlp_b1 + (size_t)i * 2048, nullptr, 0, hid, 2048, 0L, DIMD);
        if (i < NLAYER - 1) {
            mfma_gemm<64, 0, true, true, false><<<dim3(MROWS / 64, 4, 1), 256, 0, stream>>>(
                hid, 2048, 0L, w2T + (size_t)i * 512 * 2048, 2048, 0L,
                mlp_b2 + (size_t)i * DIMD, x, DIMD, x, DIMD, 0L, 2048);
        } else {
            mfma_gemm<64, 0, true, true, true><<<dim3(MROWS / 64, 4, 1), 256, 0, stream>>>(
                hid, 2048, 0L, w2T + (size_t)i * 512 * 2048, 2048, 0L,
                mlp_b2 + (size_t)i * DIMD, x, DIMD, xb, DIMD, 0L, 2048);
        }
    }

    // ---- head ----
    mfma_gemm<128, 0, true, false, false><<<dim3(MROWS / 128, 16, 1), 256, 0, stream>>>(
        xb, DIMD, 0L, wWfT, DIMD, 0L, fb, nullptr, 0, out, 2048, 0L, DIMD);
}

// Round 11
// 487.497 us; speedup vs baseline: 1.0612x; 1.0612x over previous
//
#include <hip/hip_runtime.h>
#include <hip/hip_bf16.h>
#include <math.h>

#define DIMD 512
#define NLAYER 4
#define PP 8
#define BBATCH 4
#define LBYTES 8192
#define LPATCH 1024
#define MROWS (BBATCH * LPATCH)   // 4096

#define NCHUNK 64
#define CLEN   16
#define QGS    (4 * DIMD)   // 2048

typedef __bf16 bf16x8 __attribute__((ext_vector_type(8)));
typedef float f32x4 __attribute__((ext_vector_type(4)));
typedef unsigned short u16x4 __attribute__((ext_vector_type(4)));
typedef unsigned short u16x8 __attribute__((ext_vector_type(8)));

__device__ __forceinline__ unsigned short f2bf(float f) {
    union { float f; unsigned u; } v; v.f = f;
    unsigned r = v.u + 0x7FFFu + ((v.u >> 16) & 1u);   // RNE
    return (unsigned short)(r >> 16);
}
__device__ __forceinline__ float bf2f(unsigned short u) {
    union { unsigned u; float f; } v; v.u = ((unsigned)u) << 16;
    return v.f;
}

__device__ __forceinline__ void glds16(const unsigned short* g, unsigned short* l) {
    __builtin_amdgcn_global_load_lds((__attribute__((address_space(1))) void*)g,
                                     (__attribute__((address_space(3))) void*)l,
                                     16, 0, 0);
}

// =======================================================================
// bf16 MFMA GEMM (NT): C[M,N] = act(A[M,K] @ Bt[N,K]^T + bias) (+res)
// (R5-proven structure — do not touch)
// =======================================================================
template<int TM, int ACT, bool BIAS, bool RES, bool OBF>
__global__ __launch_bounds__(256)
void mfma_gemm(const unsigned short* __restrict__ A, int lda, long aZ,
               const unsigned short* __restrict__ Bt, int ldb, long bZ,
               const float* __restrict__ bias,
               const float* __restrict__ res, int ldr,
               void* __restrict__ Cv, int ldc, long cZ, int K)
{
    constexpr int M_REP = TM / 32;
    __shared__ unsigned short As[TM * 32];
    __shared__ unsigned short Bs[128 * 32];

    const int tid = threadIdx.x;
    const int w = tid >> 6, l = tid & 63;
    const int row0 = blockIdx.x * TM;
    const int col0 = blockIdx.y * 128;
    A  += (size_t)blockIdx.z * aZ;
    Bt += (size_t)blockIdx.z * bZ;
    unsigned short* Cb = (unsigned short*)Cv + (size_t)blockIdx.z * cZ;
    float*          Cf = (float*)Cv          + (size_t)blockIdx.z * cZ;

    const int cA = w * 64 + l;
    const unsigned short* gA0 = A + (size_t)(row0 + (cA >> 2)) * lda + (cA & 3) * 8;
    const unsigned short* gB0 = Bt + (size_t)(col0 + (cA >> 2)) * ldb + (cA & 3) * 8;
    const unsigned short* gB1 = Bt + (size_t)(col0 + 64 + (cA >> 2)) * ldb + (cA & 3) * 8;
    unsigned short* lA0 = &As[w * 512];
    unsigned short* lB0 = &Bs[w * 512];
    unsigned short* lB1 = &Bs[2048 + w * 512];
    const unsigned short* gA1 = nullptr;
    unsigned short* lA1 = nullptr;
    if constexpr (TM == 128) {
        gA1 = A + (size_t)(row0 + 64 + (cA >> 2)) * lda + (cA & 3) * 8;
        lA1 = &As[2048 + w * 512];
    }

    const int wr = (w >> 1) * (TM / 2);
    const int wc = (w & 1) * 64;
    const int lr = l & 15, lk = (l >> 4) * 8;
    const int aBase = (wr + lr) * 32 + lk;
    const int bBase = (wc + lr) * 32 + lk;

    f32x4 acc[M_REP][4] = {};

    for (int k0 = 0; k0 < K; k0 += 32) {
        glds16(gA0, lA0);  gA0 += 32;
        if constexpr (TM == 128) { glds16(gA1, lA1); gA1 += 32; }
        glds16(gB0, lB0);  gB0 += 32;
        glds16(gB1, lB1);  gB1 += 32;
        __syncthreads();
        bf16x8 af[M_REP], bfr[4];
        #pragma unroll
        for (int m = 0; m < M_REP; m++)
            af[m] = *reinterpret_cast<const bf16x8*>(&As[aBase + m * 512]);
        #pragma unroll
        for (int n = 0; n < 4; n++)
            bfr[n] = *reinterpret_cast<const bf16x8*>(&Bs[bBase + n * 512]);
        #pragma unroll
        for (int m = 0; m < M_REP; m++)
            #pragma unroll
            for (int n = 0; n < 4; n++)
                acc[m][n] = __builtin_amdgcn_mfma_f32_16x16x32_bf16(
                    af[m], bfr[n], acc[m][n], 0, 0, 0);
        __syncthreads();
    }

    const int r0 = row0 + wr + (l >> 4) * 4;
    const int c0 = col0 + wc + lr;
    float bv[4] = {0.f, 0.f, 0.f, 0.f};
    if (BIAS) {
        #pragma unroll
        for (int n = 0; n < 4; n++) bv[n] = bias[c0 + n * 16];
    }
    #pragma unroll
    for (int m = 0; m < M_REP; m++) {
        #pragma unroll
        for (int j = 0; j < 4; j++) {
            const int row = r0 + m * 16 + j;
            #pragma unroll
            for (int n = 0; n < 4; n++) {
                float v = acc[m][n][j];
                if (BIAS) v += bv[n];
                if (ACT == 1) v = tanhf(v);
                if (ACT == 2) v = 0.5f * v * (1.f + erff(v * 0.70710678118f));
                if (RES) v += res[(size_t)row * ldr + c0 + n * 16];
                if (OBF) Cb[(size_t)row * ldc + c0 + n * 16] = f2bf(v);
                else     Cf[(size_t)row * ldc + c0 + n * 16] = v;
            }
        }
    }
}

// ======================= megapack: all weight preprocessing =======================
__device__ __forceinline__ void packT_body(float* sm, const float* __restrict__ in,
                                           unsigned short* __restrict__ out,
                                           int K, int N, int bx, int by)
{
    float (*t)[33] = (float(*)[33])sm;
    const int k0 = bx * 32, n0 = by * 32;
    const int tx = threadIdx.x & 31, ty = threadIdx.x >> 5;
    #pragma unroll
    for (int i = 0; i < 4; i++)
        t[ty + i * 8][tx] = in[(size_t)(k0 + ty + i * 8) * N + n0 + tx];
    __syncthreads();
    #pragma unroll
    for (int i = 0; i < 4; i++)
        out[(size_t)(n0 + ty + i * 8) * K + k0 + tx] = f2bf(t[tx][ty + i * 8]);
}

__device__ __forceinline__ void cast_body(const float* __restrict__ in,
                                          unsigned short* __restrict__ out, int blk)
{
    const long i = ((long)blk * 256 + threadIdx.x) * 8;
    float4 a = *(const float4*)(in + i);
    float4 b = *(const float4*)(in + i + 4);
    u16x8 o;
    o[0] = f2bf(a.x); o[1] = f2bf(a.y); o[2] = f2bf(a.z); o[3] = f2bf(a.w);
    o[4] = f2bf(b.x); o[5] = f2bf(b.y); o[6] = f2bf(b.z); o[7] = f2bf(b.w);
    *reinterpret_cast<u16x8*>(out + i) = o;
}

__global__ __launch_bounds__(256)
void megapack(const float* __restrict__ qkv_w, const float* __restrict__ gate_w,
              const float* __restrict__ mlp_w1, const float* __restrict__ mlp_w2,
              const float* __restrict__ hash_proj, const float* __restrict__ head_w,
              const float* __restrict__ enc_w, const float* __restrict__ dec_w,
              const float* __restrict__ byte_emb,
              const float* __restrict__ qkv_b, const float* __restrict__ gate_b,
              const float* __restrict__ dec_b, const float* __restrict__ head_b,
              unsigned short* __restrict__ wcat, unsigned short* __restrict__ w1T,
              unsigned short* __restrict__ w2T, unsigned short* __restrict__ whashT,
              unsigned short* __restrict__ hwT, unsigned short* __restrict__ encT,
              unsigned short* __restrict__ decb, unsigned short* __restrict__ embB,
              float* __restrict__ cbias, float* __restrict__ fb)
{
    __shared__ float sm[32 * 33];
    int id = blockIdx.x;
    if (id < 3072) {                 // qkv_w: z4, K512, N1536 (16x48)
        int z = id / 768, r = id % 768;
        packT_body(sm, qkv_w + (size_t)z * 512 * 1536, wcat + (size_t)z * 2048 * 512,
                   512, 1536, r % 16, r / 16);
    } else if (id < 4096) {          // gate_w: z4, K512, N512 (16x16)
        id -= 3072; int z = id / 256, r = id % 256;
        packT_body(sm, gate_w + (size_t)z * 512 * 512,
                   wcat + (size_t)z * 2048 * 512 + (size_t)1536 * 512,
                   512, 512, r % 16, r / 16);
    } else if (id < 8192) {          // mlp_w1: z4, K512, N2048 (16x64)
        id -= 4096; int z = id / 1024, r = id % 1024;
        packT_body(sm, mlp_w1 + (size_t)z * 512 * 2048, w1T + (size_t)z * 2048 * 512,
                   512, 2048, r % 16, r / 16);
    } else if (id < 12288) {         // mlp_w2: z4, K2048, N512 (64x16)
        id -= 8192; int z = id / 1024, r = id % 1024;
        packT_body(sm, mlp_w2 + (size_t)z * 2048 * 512, w2T + (size_t)z * 512 * 2048,
                   2048, 512, r % 64, r / 64);
    } else if (id < 12544) {         // hash_proj (16x16)
        id -= 12288;
        packT_body(sm, hash_proj, whashT, 512, 512, id % 16, id / 16);
    } else if (id < 12672) {         // head_w: K512, N256 (16x8)
        id -= 12544;
        packT_body(sm, head_w, hwT, 512, 256, id % 16, id / 16);
    } else if (id < 14720) {         // enc_w: z8, K512, N512 (16x16)
        id -= 12672; int z = id / 256, r = id % 256;
        packT_body(sm, enc_w + (size_t)z * 512 * 512, encT + (size_t)z * 512 * 512,
                   512, 512, r % 16, r / 16);
    } else if (id < 15744) {         // dec_w cast: 2097152 elems
        cast_body(dec_w, decb, id - 14720);
    } else if (id < 15808) {         // byte_emb cast: 131072 elems
        cast_body(byte_emb, embB, id - 15744);
    } else if (id < 15840) {         // catbias: 32 blocks
        id -= 15808;
        const int i = id >> 3;
        const int n = (id & 7) * 256 + threadIdx.x;
        cbias[i * 2048 + n] = (n < 1536) ? qkv_b[i * 1536 + n] : gate_b[i * 512 + n - 1536];
    } else {                         // fused decoder+head bias (1 block)
        const int o = threadIdx.x;
        float s = head_b[o];
        for (int d = 0; d < DIMD; d++) s = fmaf(dec_b[d], head_w[d * 256 + o], s);
        #pragma unroll
        for (int p = 0; p < PP; p++) fb[p * 256 + o] = s;
    }
}

// ---- LayerNorm: one wave per row, bf16 out ----
__global__ __launch_bounds__(256)
void ln_kernel(const float* __restrict__ x, const float* __restrict__ g,
               const float* __restrict__ b, unsigned short* __restrict__ h)
{
    const int row = blockIdx.x * 4 + (threadIdx.x >> 6);
    const int lane = threadIdx.x & 63;
    const float* xr = x + (long)row * DIMD;
    float4 v0 = *(const float4*)(xr + lane * 8);
    float4 v1 = *(const float4*)(xr + lane * 8 + 4);
    float xv[8] = {v0.x, v0.y, v0.z, v0.w, v1.x, v1.y, v1.z, v1.w};
    float s = 0.f, q = 0.f;
    #pragma unroll
    for (int j = 0; j < 8; j++) { s += xv[j]; q += xv[j] * xv[j]; }
    #pragma unroll
    for (int off = 1; off < 64; off <<= 1) {
        s += __shfl_xor(s, off);
        q += __shfl_xor(q, off);
    }
    const float mean = s * (1.f / DIMD);
    const float var  = q * (1.f / DIMD) - mean * mean;
    const float rstd = rsqrtf(var + 1e-5f);
    float4 g0 = *(const float4*)(g + lane * 8);
    float4 g1 = *(const float4*)(g + lane * 8 + 4);
    float4 b0 = *(const float4*)(b + lane * 8);
    float4 b1 = *(const float4*)(b + lane * 8 + 4);
    float gv[8] = {g0.x, g0.y, g0.z, g0.w, g1.x, g1.y, g1.z, g1.w};
    float bb[8] = {b0.x, b0.y, b0.z, b0.w, b1.x, b1.y, b1.z, b1.w};
    u16x8 o;
    #pragma unroll
    for (int j = 0; j < 8; j++) o[j] = f2bf((xv[j] - mean) * rstd * gv[j] + bb[j]);
    *reinterpret_cast<u16x8*>(h + (long)row * DIMD + lane * 8) = o;
}

// ---- fused embed+encode ----
__global__ __launch_bounds__(128)
void embed_kernel(const int* __restrict__ bytes, const float* __restrict__ E,
                  const float* __restrict__ enc_b, float* __restrict__ x0,
                  unsigned short* __restrict__ x0b)
{
    const int patch = blockIdx.x;
    __shared__ int by[PP];
    if (threadIdx.x < PP) by[threadIdx.x] = bytes[patch * PP + threadIdx.x];
    __syncthreads();
    const int o = threadIdx.x * 4;
    float4 acc = *(const float4*)(enc_b + o);
    #pragma unroll
    for (int p = 0; p < PP; p++) {
        float4 e = *(const float4*)(E + ((long)(p * 256 + by[p])) * DIMD + o);
        acc.x += e.x; acc.y += e.y; acc.z += e.z; acc.w += e.w;
    }
    *(float4*)(x0 + (long)patch * DIMD + o) = acc;
    u16x4 ob; ob[0] = f2bf(acc.x); ob[1] = f2bf(acc.y);
    ob[2] = f2bf(acc.z); ob[3] = f2bf(acc.w);
    *reinterpret_cast<u16x4*>(x0b + (long)patch * DIMD + o) = ob;
}

// ---- scan partial sums: 256 thr, 2 dims/thread, ushort2 loads ----
__global__ __launch_bounds__(256)
void scan_partial(const unsigned short* __restrict__ qg, float* __restrict__ S)
{
    const int b = blockIdx.x >> 6, c = blockIdx.x & 63, d2 = threadIdx.x * 2;
    const unsigned short* base = qg + (size_t)(b * LPATCH + c * CLEN) * QGS;
    float s0 = 0.f, s1 = 0.f;
    for (int l = 0; l < CLEN; l++) {
        ushort2 kk = *(const ushort2*)(base + l * QGS + DIMD + d2);
        ushort2 vv = *(const ushort2*)(base + l * QGS + 2 * DIMD + d2);
        s0 = fmaf(bf2f(kk.x), bf2f(vv.x), s0);
        s1 = fmaf(bf2f(kk.y), bf2f(vv.y), s1);
    }
    *(float2*)(S + (size_t)(b * NCHUNK + c) * DIMD + d2) = make_float2(s0, s1);
}

// ---- exclusive prefix over chunk sums ----
__global__ __launch_bounds__(512)
void scan_prefix(float* __restrict__ S)
{
    const int b = blockIdx.x, d = threadIdx.x;
    float run = 0.f;
    #pragma unroll 4
    for (int c = 0; c < NCHUNK; c++) {
        float v = S[(b * NCHUNK + c) * DIMD + d];
        S[(b * NCHUNK + c) * DIMD + d] = run;
        run += v;
    }
}

// ---- scan apply: 256 thr, 2 dims/thread ----
__global__ __launch_bounds__(256)
void scan_apply(const unsigned short* __restrict__ qg,
                const float* __restrict__ S, float* __restrict__ x)
{
    const int b = blockIdx.x >> 6, c = blockIdx.x & 63, d2 = threadIdx.x * 2;
    float2 kv = *(const float2*)(S + (size_t)(b * NCHUNK + c) * DIMD + d2);
    const int row0 = b * LPATCH + c * CLEN;
    for (int l = 0; l < CLEN; l++) {
        const unsigned short* qb = qg + (size_t)(row0 + l) * QGS;
        ushort2 qq = *(const ushort2*)(qb + d2);
        ushort2 kk = *(const ushort2*)(qb + DIMD + d2);
        ushort2 vv = *(const ushort2*)(qb + 2 * DIMD + d2);
        ushort2 gg = *(const ushort2*)(qb + 3 * DIMD + d2);
        kv.x = fmaf(bf2f(kk.x), bf2f(vv.x), kv.x);
        kv.y = fmaf(bf2f(kk.y), bf2f(vv.y), kv.y);
        const float sg0 = 1.f / (1.f + expf(-bf2f(gg.x)));
        const float sg1 = 1.f / (1.f + expf(-bf2f(gg.y)));
        float* xr = x + (size_t)(row0 + l) * DIMD;
        float2 xv = *(const float2*)(xr + d2);
        xv.x += bf2f(qq.x) * kv.x * sg0;
        xv.y += bf2f(qq.y) * kv.y * sg1;
        *(float2*)(xr + d2) = xv;
    }
}

extern "C" void kernel_launch(void* const* d_in, const int* in_sizes, int n_in,
                              void* d_out, int out_size, void* d_ws, size_t ws_size,
                              hipStream_t stream)
{
    (void)in_sizes; (void)n_in; (void)out_size; (void)ws_size;

    const int*   bytes_in  = (const int*)d_in[0];
    const float* byte_emb  = (const float*)d_in[1];
    const float* enc_w     = (const float*)d_in[2];
    const float* enc_b     = (const float*)d_in[3];
    const float* hash_proj = (const float*)d_in[4];
    const float* qkv_w     = (const float*)d_in[5];
    const float* qkv_b     = (const float*)d_in[6];
    const float* gate_w    = (const float*)d_in[7];
    const float* gate_b    = (const float*)d_in[8];
    const float* ln1_g     = (const float*)d_in[9];
    const float* ln1_b     = (const float*)d_in[10];
    const float* mlp_w1    = (const float*)d_in[11];
    const float* mlp_b1    = (const float*)d_in[12];
    const float* mlp_w2    = (const float*)d_in[13];
    const float* mlp_b2    = (const float*)d_in[14];
    const float* ln2_g     = (const float*)d_in[15];
    const float* ln2_b     = (const float*)d_in[16];
    const float* dec_w     = (const float*)d_in[17];
    const float* dec_b     = (const float*)d_in[18];
    const float* head_w    = (const float*)d_in[19];
    const float* head_b    = (const float*)d_in[20];
    float* out = (float*)d_out;

    // ---- workspace layout ----
    char* ws = (char*)d_ws;
    size_t o = 0;
    auto alloc = [&](size_t bytes) { char* p = ws + o; o += (bytes + 255) & ~(size_t)255; return p; };
    unsigned short* wcat   = (unsigned short*)alloc((size_t)4 * 2048 * 512 * 2);
    unsigned short* w1T    = (unsigned short*)alloc((size_t)4 * 2048 * 512 * 2);
    unsigned short* w2T    = (unsigned short*)alloc((size_t)4 * 512 * 2048 * 2);
    unsigned short* whashT = (unsigned short*)alloc((size_t)512 * 512 * 2);
    unsigned short* wWfT   = (unsigned short*)alloc((size_t)2048 * 512 * 2);
    unsigned short* encT   = (unsigned short*)alloc((size_t)8 * 512 * 512 * 2);
    unsigned short* hwT    = (unsigned short*)alloc((size_t)256 * 512 * 2);
    unsigned short* decb   = (unsigned short*)alloc((size_t)512 * 8 * 512 * 2);
    unsigned short* embB   = (unsigned short*)alloc((size_t)256 * 512 * 2);
    float* cbias           = (float*)alloc((size_t)4 * 2048 * 4);
    float* fb              = (float*)alloc(2048 * 4);
    float* E               = (float*)alloc((size_t)8 * 256 * 512 * 4);
    float* x               = (float*)alloc((size_t)MROWS * DIMD * 4);
    float* x0              = (float*)alloc((size_t)MROWS * DIMD * 4);
    unsigned short* x0b    = (unsigned short*)alloc((size_t)MROWS * DIMD * 2);
    unsigned short* h      = (unsigned short*)alloc((size_t)MROWS * DIMD * 2);
    unsigned short* xb     = (unsigned short*)alloc((size_t)MROWS * DIMD * 2);
    float* S               = (float*)alloc((size_t)BBATCH * NCHUNK * DIMD * 4);
    unsigned short* qg     = (unsigned short*)alloc((size_t)MROWS * 2048 * 2);
    unsigned short* hid    = (unsigned short*)alloc((size_t)MROWS * 2048 * 2);

    // ---- 1. all weight preprocessing (incl. fused decoder+head bias) ----
    megapack<<<dim3(15841), 256, 0, stream>>>(
        qkv_w, gate_w, mlp_w1, mlp_w2, hash_proj, head_w, enc_w, dec_w, byte_emb,
        qkv_b, gate_b, dec_b, head_b,
        wcat, w1T, w2T, whashT, hwT, encT, decb, embB, cbias, fb);

    // ---- 2. WfT[p*256+o][d] = sum_c head_wT[o][c] * dec_w[d][p][c] ----
    mfma_gemm<64, 0, false, false, true><<<dim3(4, 4, 8), 256, 0, stream>>>(
        hwT, 512, 0L, decb, PP * 512, 512L,
        nullptr, nullptr, 0, wWfT, 512, (long)256 * 512, 512);

    // ---- 3. E[p] = byte_emb @ enc_w[p] ----
    mfma_gemm<64, 0, false, false, false><<<dim3(4, 4, 8), 256, 0, stream>>>(
        embB, 512, 0L, encT, 512, (long)512 * 512,
        nullptr, nullptr, 0, E, 512, (long)256 * 512, 512);

    embed_kernel<<<dim3(MROWS), dim3(128), 0, stream>>>(bytes_in, E, enc_b, x0, x0b);

    // ---- 4. x = x0 + tanh(x0 @ hash_proj) ----
    mfma_gemm<64, 1, false, true, false><<<dim3(MROWS / 64, 4, 1), 256, 0, stream>>>(
        x0b, DIMD, 0L, whashT, DIMD, 0L, nullptr, x0, DIMD, x, DIMD, 0L, DIMD);

    for (int i = 0; i < NLAYER; i++) {
        ln_kernel<<<dim3(MROWS / 4), 256, 0, stream>>>(x, ln1_g + i * DIMD, ln1_b + i * DIMD, h);
        mfma_gemm<128, 0, true, false, true><<<dim3(MROWS / 128, 16, 1), 256, 0, stream>>>(
            h, DIMD, 0L, wcat + (size_t)i * 2048 * 512, DIMD, 0L,
            cbias + (size_t)i * 2048, nullptr, 0, qg, 2048, 0L, DIMD);
        scan_partial<<<dim3(BBATCH * NCHUNK), 256, 0, stream>>>(qg, S);
        scan_prefix<<<dim3(BBATCH), dim3(512), 0, stream>>>(S);
        scan_apply<<<dim3(BBATCH * NCHUNK), 256, 0, stream>>>(qg, S, x);
        ln_kernel<<<dim3(MROWS / 4), 256, 0, stream>>>(x, ln2_g + i * DIMD, ln2_b + i * DIMD, h);
        mfma_gemm<128, 2, true, false, true><<<dim3(MROWS / 128, 16, 1), 256, 0, stream>>>(
            h, DIMD, 0L, w1T + (size_t)i * 2048 * 512, DIMD, 0L,
            mlp_b1 + (size_t)i * 2048, nullptr, 0, hid, 2048, 0L, DIMD);
        if (i < NLAYER - 1) {
            mfma_gemm<64, 0, true, true, false><<<dim3(MROWS / 64, 4, 1), 256, 0, stream>>>(
                hid, 2048, 0L, w2T + (size_t)i * 512 * 2048, 2048, 0L,
                mlp_b2 + (size_t)i * DIMD, x, DIMD, x, DIMD, 0L, 2048);
        } else {
            mfma_gemm<64, 0, true, true, true><<<dim3(MROWS / 64, 4, 1), 256, 0, stream>>>(
                hid, 2048, 0L, w2T + (size_t)i * 512 * 2048, 2048, 0L,
                mlp_b2 + (size_t)i * DIMD, x, DIMD, xb, DIMD, 0L, 2048);
        }
    }

    // ---- head ----
    mfma_gemm<128, 0, true, false, false><<<dim3(MROWS / 128, 16, 1), 256, 0, stream>>>(
        xb, DIMD, 0L, wWfT, DIMD, 0L, fb, nullptr, 0, out, 2048, 0L, DIMD);
}

// Round 12
// 477.807 us; speedup vs baseline: 1.0827x; 1.0203x over previous
//
#include <hip/hip_runtime.h>
#include <hip/hip_bf16.h>
#include <math.h>

#define DIMD 512
#define NLAYER 4
#define PP 8
#define BBATCH 4
#define LBYTES 8192
#define LPATCH 1024
#define MROWS (BBATCH * LPATCH)   // 4096

#define NCHUNK 64
#define CLEN   16
#define QGS    (4 * DIMD)   // 2048

typedef __bf16 bf16x8 __attribute__((ext_vector_type(8)));
typedef float f32x4 __attribute__((ext_vector_type(4)));
typedef unsigned short u16x4 __attribute__((ext_vector_type(4)));
typedef unsigned short u16x8 __attribute__((ext_vector_type(8)));

__device__ __forceinline__ unsigned short f2bf(float f) {
    union { float f; unsigned u; } v; v.f = f;
    unsigned r = v.u + 0x7FFFu + ((v.u >> 16) & 1u);   // RNE
    return (unsigned short)(r >> 16);
}
__device__ __forceinline__ float bf2f(unsigned short u) {
    union { unsigned u; float f; } v; v.u = ((unsigned)u) << 16;
    return v.f;
}

__device__ __forceinline__ void glds16(const unsigned short* g, unsigned short* l) {
    __builtin_amdgcn_global_load_lds((__attribute__((address_space(1))) void*)g,
                                     (__attribute__((address_space(3))) void*)l,
                                     16, 0, 0);
}

// =======================================================================
// bf16 MFMA GEMM (NT): C[M,N] = act(A[M,K] @ Bt[N,K]^T + bias) (+res)
// (R5-proven structure — do not touch)
// =======================================================================
template<int TM, int ACT, bool BIAS, bool RES, bool OBF>
__global__ __launch_bounds__(256)
void mfma_gemm(const unsigned short* __restrict__ A, int lda, long aZ,
               const unsigned short* __restrict__ Bt, int ldb, long bZ,
               const float* __restrict__ bias,
               const float* __restrict__ res, int ldr,
               void* __restrict__ Cv, int ldc, long cZ, int K)
{
    constexpr int M_REP = TM / 32;
    __shared__ unsigned short As[TM * 32];
    __shared__ unsigned short Bs[128 * 32];

    const int tid = threadIdx.x;
    const int w = tid >> 6, l = tid & 63;
    const int row0 = blockIdx.x * TM;
    const int col0 = blockIdx.y * 128;
    A  += (size_t)blockIdx.z * aZ;
    Bt += (size_t)blockIdx.z * bZ;
    unsigned short* Cb = (unsigned short*)Cv + (size_t)blockIdx.z * cZ;
    float*          Cf = (float*)Cv          + (size_t)blockIdx.z * cZ;

    const int cA = w * 64 + l;
    const unsigned short* gA0 = A + (size_t)(row0 + (cA >> 2)) * lda + (cA & 3) * 8;
    const unsigned short* gB0 = Bt + (size_t)(col0 + (cA >> 2)) * ldb + (cA & 3) * 8;
    const unsigned short* gB1 = Bt + (size_t)(col0 + 64 + (cA >> 2)) * ldb + (cA & 3) * 8;
    unsigned short* lA0 = &As[w * 512];
    unsigned short* lB0 = &Bs[w * 512];
    unsigned short* lB1 = &Bs[2048 + w * 512];
    const unsigned short* gA1 = nullptr;
    unsigned short* lA1 = nullptr;
    if constexpr (TM == 128) {
        gA1 = A + (size_t)(row0 + 64 + (cA >> 2)) * lda + (cA & 3) * 8;
        lA1 = &As[2048 + w * 512];
    }

    const int wr = (w >> 1) * (TM / 2);
    const int wc = (w & 1) * 64;
    const int lr = l & 15, lk = (l >> 4) * 8;
    const int aBase = (wr + lr) * 32 + lk;
    const int bBase = (wc + lr) * 32 + lk;

    f32x4 acc[M_REP][4] = {};

    for (int k0 = 0; k0 < K; k0 += 32) {
        glds16(gA0, lA0);  gA0 += 32;
        if constexpr (TM == 128) { glds16(gA1, lA1); gA1 += 32; }
        glds16(gB0, lB0);  gB0 += 32;
        glds16(gB1, lB1);  gB1 += 32;
        __syncthreads();
        bf16x8 af[M_REP], bfr[4];
        #pragma unroll
        for (int m = 0; m < M_REP; m++)
            af[m] = *reinterpret_cast<const bf16x8*>(&As[aBase + m * 512]);
        #pragma unroll
        for (int n = 0; n < 4; n++)
            bfr[n] = *reinterpret_cast<const bf16x8*>(&Bs[bBase + n * 512]);
        #pragma unroll
        for (int m = 0; m < M_REP; m++)
            #pragma unroll
            for (int n = 0; n < 4; n++)
                acc[m][n] = __builtin_amdgcn_mfma_f32_16x16x32_bf16(
                    af[m], bfr[n], acc[m][n], 0, 0, 0);
        __syncthreads();
    }

    const int r0 = row0 + wr + (l >> 4) * 4;
    const int c0 = col0 + wc + lr;
    float bv[4] = {0.f, 0.f, 0.f, 0.f};
    if (BIAS) {
        #pragma unroll
        for (int n = 0; n < 4; n++) bv[n] = bias[c0 + n * 16];
    }
    #pragma unroll
    for (int m = 0; m < M_REP; m++) {
        #pragma unroll
        for (int j = 0; j < 4; j++) {
            const int row = r0 + m * 16 + j;
            #pragma unroll
            for (int n = 0; n < 4; n++) {
                float v = acc[m][n][j];
                if (BIAS) v += bv[n];
                if (ACT == 1) v = tanhf(v);
                if (ACT == 2) v = 0.5f * v * (1.f + erff(v * 0.70710678118f));
                if (RES) v += res[(size_t)row * ldr + c0 + n * 16];
                if (OBF) Cb[(size_t)row * ldc + c0 + n * 16] = f2bf(v);
                else     Cf[(size_t)row * ldc + c0 + n * 16] = v;
            }
        }
    }
}

// ======================= megapack: all weight preprocessing =======================
__device__ __forceinline__ void packT_body(float* sm, const float* __restrict__ in,
                                           unsigned short* __restrict__ out,
                                           int K, int N, int bx, int by)
{
    float (*t)[33] = (float(*)[33])sm;
    const int k0 = bx * 32, n0 = by * 32;
    const int tx = threadIdx.x & 31, ty = threadIdx.x >> 5;
    #pragma unroll
    for (int i = 0; i < 4; i++)
        t[ty + i * 8][tx] = in[(size_t)(k0 + ty + i * 8) * N + n0 + tx];
    __syncthreads();
    #pragma unroll
    for (int i = 0; i < 4; i++)
        out[(size_t)(n0 + ty + i * 8) * K + k0 + tx] = f2bf(t[tx][ty + i * 8]);
}

__device__ __forceinline__ void cast_body(const float* __restrict__ in,
                                          unsigned short* __restrict__ out, int blk)
{
    const long i = ((long)blk * 256 + threadIdx.x) * 8;
    float4 a = *(const float4*)(in + i);
    float4 b = *(const float4*)(in + i + 4);
    u16x8 o;
    o[0] = f2bf(a.x); o[1] = f2bf(a.y); o[2] = f2bf(a.z); o[3] = f2bf(a.w);
    o[4] = f2bf(b.x); o[5] = f2bf(b.y); o[6] = f2bf(b.z); o[7] = f2bf(b.w);
    *reinterpret_cast<u16x8*>(out + i) = o;
}

__global__ __launch_bounds__(256)
void megapack(const float* __restrict__ qkv_w, const float* __restrict__ gate_w,
              const float* __restrict__ mlp_w1, const float* __restrict__ mlp_w2,
              const float* __restrict__ hash_proj, const float* __restrict__ head_w,
              const float* __restrict__ enc_w, const float* __restrict__ dec_w,
              const float* __restrict__ byte_emb,
              const float* __restrict__ qkv_b, const float* __restrict__ gate_b,
              const float* __restrict__ dec_b, const float* __restrict__ head_b,
              unsigned short* __restrict__ wcat, unsigned short* __restrict__ w1T,
              unsigned short* __restrict__ w2T, unsigned short* __restrict__ whashT,
              unsigned short* __restrict__ hwT, unsigned short* __restrict__ encT,
              unsigned short* __restrict__ decb, unsigned short* __restrict__ embB,
              float* __restrict__ cbias, float* __restrict__ fb)
{
    __shared__ float sm[32 * 33];
    int id = blockIdx.x;
    if (id < 3072) {                 // qkv_w: z4, K512, N1536 (16x48)
        int z = id / 768, r = id % 768;
        packT_body(sm, qkv_w + (size_t)z * 512 * 1536, wcat + (size_t)z * 2048 * 512,
                   512, 1536, r % 16, r / 16);
    } else if (id < 4096) {          // gate_w: z4, K512, N512 (16x16)
        id -= 3072; int z = id / 256, r = id % 256;
        packT_body(sm, gate_w + (size_t)z * 512 * 512,
                   wcat + (size_t)z * 2048 * 512 + (size_t)1536 * 512,
                   512, 512, r % 16, r / 16);
    } else if (id < 8192) {          // mlp_w1: z4, K512, N2048 (16x64)
        id -= 4096; int z = id / 1024, r = id % 1024;
        packT_body(sm, mlp_w1 + (size_t)z * 512 * 2048, w1T + (size_t)z * 2048 * 512,
                   512, 2048, r % 16, r / 16);
    } else if (id < 12288) {         // mlp_w2: z4, K2048, N512 (64x16)
        id -= 8192; int z = id / 1024, r = id % 1024;
        packT_body(sm, mlp_w2 + (size_t)z * 2048 * 512, w2T + (size_t)z * 512 * 2048,
                   2048, 512, r % 64, r / 64);
    } else if (id < 12544) {         // hash_proj (16x16)
        id -= 12288;
        packT_body(sm, hash_proj, whashT, 512, 512, id % 16, id / 16);
    } else if (id < 12672) {         // head_w: K512, N256 (16x8)
        id -= 12544;
        packT_body(sm, head_w, hwT, 512, 256, id % 16, id / 16);
    } else if (id < 14720) {         // enc_w: z8, K512, N512 (16x16)
        id -= 12672; int z = id / 256, r = id % 256;
        packT_body(sm, enc_w + (size_t)z * 512 * 512, encT + (size_t)z * 512 * 512,
                   512, 512, r % 16, r / 16);
    } else if (id < 15744) {         // dec_w cast: 2097152 elems
        cast_body(dec_w, decb, id - 14720);
    } else if (id < 15808) {         // byte_emb cast: 131072 elems
        cast_body(byte_emb, embB, id - 15744);
    } else if (id < 15840) {         // catbias: 32 blocks
        id -= 15808;
        const int i = id >> 3;
        const int n = (id & 7) * 256 + threadIdx.x;
        cbias[i * 2048 + n] = (n < 1536) ? qkv_b[i * 1536 + n] : gate_b[i * 512 + n - 1536];
    } else {                         // fused decoder+head bias (1 block)
        const int o = threadIdx.x;
        float s = head_b[o];
        for (int d = 0; d < DIMD; d++) s = fmaf(dec_b[d], head_w[d * 256 + o], s);
        #pragma unroll
        for (int p = 0; p < PP; p++) fb[p * 256 + o] = s;
    }
}

// ---- LayerNorm: one wave per row, bf16 out ----
__global__ __launch_bounds__(256)
void ln_kernel(const float* __restrict__ x, const float* __restrict__ g,
               const float* __restrict__ b, unsigned short* __restrict__ h)
{
    const int row = blockIdx.x * 4 + (threadIdx.x >> 6);
    const int lane = threadIdx.x & 63;
    const float* xr = x + (long)row * DIMD;
    float4 v0 = *(const float4*)(xr + lane * 8);
    float4 v1 = *(const float4*)(xr + lane * 8 + 4);
    float xv[8] = {v0.x, v0.y, v0.z, v0.w, v1.x, v1.y, v1.z, v1.w};
    float s = 0.f, q = 0.f;
    #pragma unroll
    for (int j = 0; j < 8; j++) { s += xv[j]; q += xv[j] * xv[j]; }
    #pragma unroll
    for (int off = 1; off < 64; off <<= 1) {
        s += __shfl_xor(s, off);
        q += __shfl_xor(q, off);
    }
    const float mean = s * (1.f / DIMD);
    const float var  = q * (1.f / DIMD) - mean * mean;
    const float rstd = rsqrtf(var + 1e-5f);
    float4 g0 = *(const float4*)(g + lane * 8);
    float4 g1 = *(const float4*)(g + lane * 8 + 4);
    float4 b0 = *(const float4*)(b + lane * 8);
    float4 b1 = *(const float4*)(b + lane * 8 + 4);
    float gv[8] = {g0.x, g0.y, g0.z, g0.w, g1.x, g1.y, g1.z, g1.w};
    float bb[8] = {b0.x, b0.y, b0.z, b0.w, b1.x, b1.y, b1.z, b1.w};
    u16x8 o;
    #pragma unroll
    for (int j = 0; j < 8; j++) o[j] = f2bf((xv[j] - mean) * rstd * gv[j] + bb[j]);
    *reinterpret_cast<u16x8*>(h + (long)row * DIMD + lane * 8) = o;
}

// ---- fused embed+encode ----
__global__ __launch_bounds__(128)
void embed_kernel(const int* __restrict__ bytes, const float* __restrict__ E,
                  const float* __restrict__ enc_b, float* __restrict__ x0,
                  unsigned short* __restrict__ x0b)
{
    const int patch = blockIdx.x;
    __shared__ int by[PP];
    if (threadIdx.x < PP) by[threadIdx.x] = bytes[patch * PP + threadIdx.x];
    __syncthreads();
    const int o = threadIdx.x * 4;
    float4 acc = *(const float4*)(enc_b + o);
    #pragma unroll
    for (int p = 0; p < PP; p++) {
        float4 e = *(const float4*)(E + ((long)(p * 256 + by[p])) * DIMD + o);
        acc.x += e.x; acc.y += e.y; acc.z += e.z; acc.w += e.w;
    }
    *(float4*)(x0 + (long)patch * DIMD + o) = acc;
    u16x4 ob; ob[0] = f2bf(acc.x); ob[1] = f2bf(acc.y);
    ob[2] = f2bf(acc.z); ob[3] = f2bf(acc.w);
    *reinterpret_cast<u16x4*>(x0b + (long)patch * DIMD + o) = ob;
}

// ---- scan partial sums: 256 thr, 2 dims/thread, ushort2 loads ----
__global__ __launch_bounds__(256)
void scan_partial(const unsigned short* __restrict__ qg, float* __restrict__ S)
{
    const int b = blockIdx.x >> 6, c = blockIdx.x & 63, d2 = threadIdx.x * 2;
    const unsigned short* base = qg + (size_t)(b * LPATCH + c * CLEN) * QGS;
    float s0 = 0.f, s1 = 0.f;
    for (int l = 0; l < CLEN; l++) {
        ushort2 kk = *(const ushort2*)(base + l * QGS + DIMD + d2);
        ushort2 vv = *(const ushort2*)(base + l * QGS + 2 * DIMD + d2);
        s0 = fmaf(bf2f(kk.x), bf2f(vv.x), s0);
        s1 = fmaf(bf2f(kk.y), bf2f(vv.y), s1);
    }
    *(float2*)(S + (size_t)(b * NCHUNK + c) * DIMD + d2) = make_float2(s0, s1);
}

// ---- exclusive prefix over chunk sums ----
__global__ __launch_bounds__(512)
void scan_prefix(float* __restrict__ S)
{
    const int b = blockIdx.x, d = threadIdx.x;
    float run = 0.f;
    #pragma unroll 4
    for (int c = 0; c < NCHUNK; c++) {
        float v = S[(b * NCHUNK + c) * DIMD + d];
        S[(b * NCHUNK + c) * DIMD + d] = run;
        run += v;
    }
}

// ---- scan apply: 256 thr, 2 dims/thread ----
__global__ __launch_bounds__(256)
void scan_apply(const unsigned short* __restrict__ qg,
                const float* __restrict__ S, float* __restrict__ x)
{
    const int b = blockIdx.x >> 6, c = blockIdx.x & 63, d2 = threadIdx.x * 2;
    float2 kv = *(const float2*)(S + (size_t)(b * NCHUNK + c) * DIMD + d2);
    const int row0 = b * LPATCH + c * CLEN;
    for (int l = 0; l < CLEN; l++) {
        const unsigned short* qb = qg + (size_t)(row0 + l) * QGS;
        ushort2 qq = *(const ushort2*)(qb + d2);
        ushort2 kk = *(const ushort2*)(qb + DIMD + d2);
        ushort2 vv = *(const ushort2*)(qb + 2 * DIMD + d2);
        ushort2 gg = *(const ushort2*)(qb + 3 * DIMD + d2);
        kv.x = fmaf(bf2f(kk.x), bf2f(vv.x), kv.x);
        kv.y = fmaf(bf2f(kk.y), bf2f(vv.y), kv.y);
        const float sg0 = 1.f / (1.f + expf(-bf2f(gg.x)));
        const float sg1 = 1.f / (1.f + expf(-bf2f(gg.y)));
        float* xr = x + (size_t)(row0 + l) * DIMD;
        float2 xv = *(const float2*)(xr + d2);
        xv.x += bf2f(qq.x) * kv.x * sg0;
        xv.y += bf2f(qq.y) * kv.y * sg1;
        *(float2*)(xr + d2) = xv;
    }
}

extern "C" void kernel_launch(void* const* d_in, const int* in_sizes, int n_in,
                              void* d_out, int out_size, void* d_ws, size_t ws_size,
                              hipStream_t stream)
{
    (void)in_sizes; (void)n_in; (void)out_size; (void)ws_size;

    const int*   bytes_in  = (const int*)d_in[0];
    const float* byte_emb  = (const float*)d_in[1];
    const float* enc_w     = (const float*)d_in[2];
    const float* enc_b     = (const float*)d_in[3];
    const float* hash_proj = (const float*)d_in[4];
    const float* qkv_w     = (const float*)d_in[5];
    const float* qkv_b     = (const float*)d_in[6];
    const float* gate_w    = (const float*)d_in[7];
    const float* gate_b    = (const float*)d_in[8];
    const float* ln1_g     = (const float*)d_in[9];
    const float* ln1_b     = (const float*)d_in[10];
    const float* mlp_w1    = (const float*)d_in[11];
    const float* mlp_b1    = (const float*)d_in[12];
    const float* mlp_w2    = (const float*)d_in[13];
    const float* mlp_b2    = (const float*)d_in[14];
    const float* ln2_g     = (const float*)d_in[15];
    const float* ln2_b     = (const float*)d_in[16];
    const float* dec_w     = (const float*)d_in[17];
    const float* dec_b     = (const float*)d_in[18];
    const float* head_w    = (const float*)d_in[19];
    const float* head_b    = (const float*)d_in[20];
    float* out = (float*)d_out;

    // ---- workspace layout ----
    char* ws = (char*)d_ws;
    size_t o = 0;
    auto alloc = [&](size_t bytes) { char* p = ws + o; o += (bytes + 255) & ~(size_t)255; return p; };
    unsigned short* wcat   = (unsigned short*)alloc((size_t)4 * 2048 * 512 * 2);
    unsigned short* w1T    = (unsigned short*)alloc((size_t)4 * 2048 * 512 * 2);
    unsigned short* w2T    = (unsigned short*)alloc((size_t)4 * 512 * 2048 * 2);
    unsigned short* whashT = (unsigned short*)alloc((size_t)512 * 512 * 2);
    unsigned short* wWfT   = (unsigned short*)alloc((size_t)2048 * 512 * 2);
    unsigned short* encT   = (unsigned short*)alloc((size_t)8 * 512 * 512 * 2);
    unsigned short* hwT    = (unsigned short*)alloc((size_t)256 * 512 * 2);
    unsigned short* decb   = (unsigned short*)alloc((size_t)512 * 8 * 512 * 2);
    unsigned short* embB   = (unsigned short*)alloc((size_t)256 * 512 * 2);
    float* cbias           = (float*)alloc((size_t)4 * 2048 * 4);
    float* fb              = (float*)alloc(2048 * 4);
    float* E               = (float*)alloc((size_t)8 * 256 * 512 * 4);
    float* x               = (float*)alloc((size_t)MROWS * DIMD * 4);
    float* x0              = (float*)alloc((size_t)MROWS * DIMD * 4);
    unsigned short* x0b    = (unsigned short*)alloc((size_t)MROWS * DIMD * 2);
    unsigned short* h      = (unsigned short*)alloc((size_t)MROWS * DIMD * 2);
    unsigned short* xb     = (unsigned short*)alloc((size_t)MROWS * DIMD * 2);
    float* S               = (float*)alloc((size_t)BBATCH * NCHUNK * DIMD * 4);
    unsigned short* qg     = (unsigned short*)alloc((size_t)MROWS * 2048 * 2);
    unsigned short* hid    = (unsigned short*)alloc((size_t)MROWS * 2048 * 2);

    // ---- 1. all weight preprocessing (incl. fused decoder+head bias) ----
    megapack<<<dim3(15841), 256, 0, stream>>>(
        qkv_w, gate_w, mlp_w1, mlp_w2, hash_proj, head_w, enc_w, dec_w, byte_emb,
        qkv_b, gate_b, dec_b, head_b,
        wcat, w1T, w2T, whashT, hwT, encT, decb, embB, cbias, fb);

    // ---- 2. WfT[p*256+o][d] = sum_c head_wT[o][c] * dec_w[d][p][c] ----
    mfma_gemm<64, 0, false, false, true><<<dim3(4, 4, 8), 256, 0, stream>>>(
        hwT, 512, 0L, decb, PP * 512, 512L,
        nullptr, nullptr, 0, wWfT, 512, (long)256 * 512, 512);

    // ---- 3. E[p] = byte_emb @ enc_w[p] ----
    mfma_gemm<64, 0, false, false, false><<<dim3(4, 4, 8), 256, 0, stream>>>(
        embB, 512, 0L, encT, 512, (long)512 * 512,
        nullptr, nullptr, 0, E, 512, (long)256 * 512, 512);

    embed_kernel<<<dim3(MROWS), dim3(128), 0, stream>>>(bytes_in, E, enc_b, x0, x0b);

    // ---- 4. x = x0 + tanh(x0 @ hash_proj) ----
    mfma_gemm<64, 1, false, true, false><<<dim3(MROWS / 64, 4, 1), 256, 0, stream>>>(
        x0b, DIMD, 0L, whashT, DIMD, 0L, nullptr, x0, DIMD, x, DIMD, 0L, DIMD);

    for (int i = 0; i < NLAYER; i++) {
        ln_kernel<<<dim3(MROWS / 4), 256, 0, stream>>>(x, ln1_g + i * DIMD, ln1_b + i * DIMD, h);
        // TM=64: 1024 blocks (4/CU) instead of 512 (2/CU) — occupancy experiment
        mfma_gemm<64, 0, true, false, true><<<dim3(MROWS / 64, 16, 1), 256, 0, stream>>>(
            h, DIMD, 0L, wcat + (size_t)i * 2048 * 512, DIMD, 0L,
            cbias + (size_t)i * 2048, nullptr, 0, qg, 2048, 0L, DIMD);
        scan_partial<<<dim3(BBATCH * NCHUNK), 256, 0, stream>>>(qg, S);
        scan_prefix<<<dim3(BBATCH), dim3(512), 0, stream>>>(S);
        scan_apply<<<dim3(BBATCH * NCHUNK), 256, 0, stream>>>(qg, S, x);
        ln_kernel<<<dim3(MROWS / 4), 256, 0, stream>>>(x, ln2_g + i * DIMD, ln2_b + i * DIMD, h);
        mfma_gemm<64, 2, true, false, true><<<dim3(MROWS / 64, 16, 1), 256, 0, stream>>>(
            h, DIMD, 0L, w1T + (size_t)i * 2048 * 512, DIMD, 0L,
            mlp_b1 + (size_t)i * 2048, nullptr, 0, hid, 2048, 0L, DIMD);
        if (i < NLAYER - 1) {
            mfma_gemm<64, 0, true, true, false><<<dim3(MROWS / 64, 4, 1), 256, 0, stream>>>(
                hid, 2048, 0L, w2T + (size_t)i * 512 * 2048, 2048, 0L,
                mlp_b2 + (size_t)i * DIMD, x, DIMD, x, DIMD, 0L, 2048);
        } else {
            mfma_gemm<64, 0, true, true, true><<<dim3(MROWS / 64, 4, 1), 256, 0, stream>>>(
                hid, 2048, 0L, w2T + (size_t)i * 512 * 2048, 2048, 0L,
                mlp_b2 + (size_t)i * DIMD, x, DIMD, xb, DIMD, 0L, 2048);
        }
    }

    // ---- head ----
    mfma_gemm<64, 0, true, false, false><<<dim3(MROWS / 64, 16, 1), 256, 0, stream>>>(
        xb, DIMD, 0L, wWfT, DIMD, 0L, fb, nullptr, 0, out, 2048, 0L, DIMD);
}

// Round 13
// 469.103 us; speedup vs baseline: 1.1028x; 1.0186x over previous
//
#include <hip/hip_runtime.h>
#include <hip/hip_bf16.h>
#include <math.h>

#define DIMD 512
#define NLAYER 4
#define PP 8
#define BBATCH 4
#define LBYTES 8192
#define LPATCH 1024
#define MROWS (BBATCH * LPATCH)   // 4096

#define NCHUNK 64
#define CLEN   16
#define QGS    (4 * DIMD)   // 2048

typedef __bf16 bf16x8 __attribute__((ext_vector_type(8)));
typedef float f32x4 __attribute__((ext_vector_type(4)));
typedef unsigned short u16x4 __attribute__((ext_vector_type(4)));
typedef unsigned short u16x8 __attribute__((ext_vector_type(8)));

__device__ __forceinline__ unsigned short f2bf(float f) {
    union { float f; unsigned u; } v; v.f = f;
    unsigned r = v.u + 0x7FFFu + ((v.u >> 16) & 1u);   // RNE
    return (unsigned short)(r >> 16);
}
__device__ __forceinline__ float bf2f(unsigned short u) {
    union { unsigned u; float f; } v; v.u = ((unsigned)u) << 16;
    return v.f;
}

__device__ __forceinline__ void glds16(const unsigned short* g, unsigned short* l) {
    __builtin_amdgcn_global_load_lds((__attribute__((address_space(1))) void*)g,
                                     (__attribute__((address_space(3))) void*)l,
                                     16, 0, 0);
}

// =======================================================================
// bf16 MFMA GEMM (NT): C[M,N] = act(A[M,K] @ Bt[N,K]^T + bias) (+res)
// (R5-proven structure — do not touch)
// =======================================================================
template<int TM, int ACT, bool BIAS, bool RES, bool OBF>
__global__ __launch_bounds__(256)
void mfma_gemm(const unsigned short* __restrict__ A, int lda, long aZ,
               const unsigned short* __restrict__ Bt, int ldb, long bZ,
               const float* __restrict__ bias,
               const float* __restrict__ res, int ldr,
               void* __restrict__ Cv, int ldc, long cZ, int K)
{
    constexpr int M_REP = TM / 32;
    __shared__ unsigned short As[TM * 32];
    __shared__ unsigned short Bs[128 * 32];

    const int tid = threadIdx.x;
    const int w = tid >> 6, l = tid & 63;
    const int row0 = blockIdx.x * TM;
    const int col0 = blockIdx.y * 128;
    A  += (size_t)blockIdx.z * aZ;
    Bt += (size_t)blockIdx.z * bZ;
    unsigned short* Cb = (unsigned short*)Cv + (size_t)blockIdx.z * cZ;
    float*          Cf = (float*)Cv          + (size_t)blockIdx.z * cZ;

    const int cA = w * 64 + l;
    const unsigned short* gA0 = A + (size_t)(row0 + (cA >> 2)) * lda + (cA & 3) * 8;
    const unsigned short* gB0 = Bt + (size_t)(col0 + (cA >> 2)) * ldb + (cA & 3) * 8;
    const unsigned short* gB1 = Bt + (size_t)(col0 + 64 + (cA >> 2)) * ldb + (cA & 3) * 8;
    unsigned short* lA0 = &As[w * 512];
    unsigned short* lB0 = &Bs[w * 512];
    unsigned short* lB1 = &Bs[2048 + w * 512];
    const unsigned short* gA1 = nullptr;
    unsigned short* lA1 = nullptr;
    if constexpr (TM == 128) {
        gA1 = A + (size_t)(row0 + 64 + (cA >> 2)) * lda + (cA & 3) * 8;
        lA1 = &As[2048 + w * 512];
    }

    const int wr = (w >> 1) * (TM / 2);
    const int wc = (w & 1) * 64;
    const int lr = l & 15, lk = (l >> 4) * 8;
    const int aBase = (wr + lr) * 32 + lk;
    const int bBase = (wc + lr) * 32 + lk;

    f32x4 acc[M_REP][4] = {};

    for (int k0 = 0; k0 < K; k0 += 32) {
        glds16(gA0, lA0);  gA0 += 32;
        if constexpr (TM == 128) { glds16(gA1, lA1); gA1 += 32; }
        glds16(gB0, lB0);  gB0 += 32;
        glds16(gB1, lB1);  gB1 += 32;
        __syncthreads();
        bf16x8 af[M_REP], bfr[4];
        #pragma unroll
        for (int m = 0; m < M_REP; m++)
            af[m] = *reinterpret_cast<const bf16x8*>(&As[aBase + m * 512]);
        #pragma unroll
        for (int n = 0; n < 4; n++)
            bfr[n] = *reinterpret_cast<const bf16x8*>(&Bs[bBase + n * 512]);
        #pragma unroll
        for (int m = 0; m < M_REP; m++)
            #pragma unroll
            for (int n = 0; n < 4; n++)
                acc[m][n] = __builtin_amdgcn_mfma_f32_16x16x32_bf16(
                    af[m], bfr[n], acc[m][n], 0, 0, 0);
        __syncthreads();
    }

    const int r0 = row0 + wr + (l >> 4) * 4;
    const int c0 = col0 + wc + lr;
    float bv[4] = {0.f, 0.f, 0.f, 0.f};
    if (BIAS) {
        #pragma unroll
        for (int n = 0; n < 4; n++) bv[n] = bias[c0 + n * 16];
    }
    #pragma unroll
    for (int m = 0; m < M_REP; m++) {
        #pragma unroll
        for (int j = 0; j < 4; j++) {
            const int row = r0 + m * 16 + j;
            #pragma unroll
            for (int n = 0; n < 4; n++) {
                float v = acc[m][n][j];
                if (BIAS) v += bv[n];
                if (ACT == 1) v = tanhf(v);
                if (ACT == 2) v = 0.5f * v * (1.f + erff(v * 0.70710678118f));
                if (RES) v += res[(size_t)row * ldr + c0 + n * 16];
                if (OBF) Cb[(size_t)row * ldc + c0 + n * 16] = f2bf(v);
                else     Cf[(size_t)row * ldc + c0 + n * 16] = v;
            }
        }
    }
}

// ======================= megapack: all weight preprocessing =======================
__device__ __forceinline__ void packT_body(float* sm, const float* __restrict__ in,
                                           unsigned short* __restrict__ out,
                                           int K, int N, int bx, int by)
{
    float (*t)[33] = (float(*)[33])sm;
    const int k0 = bx * 32, n0 = by * 32;
    const int tx = threadIdx.x & 31, ty = threadIdx.x >> 5;
    #pragma unroll
    for (int i = 0; i < 4; i++)
        t[ty + i * 8][tx] = in[(size_t)(k0 + ty + i * 8) * N + n0 + tx];
    __syncthreads();
    #pragma unroll
    for (int i = 0; i < 4; i++)
        out[(size_t)(n0 + ty + i * 8) * K + k0 + tx] = f2bf(t[tx][ty + i * 8]);
}

__device__ __forceinline__ void cast_body(const float* __restrict__ in,
                                          unsigned short* __restrict__ out, int blk)
{
    const long i = ((long)blk * 256 + threadIdx.x) * 8;
    float4 a = *(const float4*)(in + i);
    float4 b = *(const float4*)(in + i + 4);
    u16x8 o;
    o[0] = f2bf(a.x); o[1] = f2bf(a.y); o[2] = f2bf(a.z); o[3] = f2bf(a.w);
    o[4] = f2bf(b.x); o[5] = f2bf(b.y); o[6] = f2bf(b.z); o[7] = f2bf(b.w);
    *reinterpret_cast<u16x8*>(out + i) = o;
}

__global__ __launch_bounds__(256)
void megapack(const float* __restrict__ qkv_w, const float* __restrict__ gate_w,
              const float* __restrict__ mlp_w1, const float* __restrict__ mlp_w2,
              const float* __restrict__ hash_proj, const float* __restrict__ head_w,
              const float* __restrict__ enc_w, const float* __restrict__ dec_w,
              const float* __restrict__ byte_emb,
              const float* __restrict__ qkv_b, const float* __restrict__ gate_b,
              const float* __restrict__ dec_b, const float* __restrict__ head_b,
              unsigned short* __restrict__ wcat, unsigned short* __restrict__ w1T,
              unsigned short* __restrict__ w2T, unsigned short* __restrict__ whashT,
              unsigned short* __restrict__ hwT, unsigned short* __restrict__ encT,
              unsigned short* __restrict__ decb, unsigned short* __restrict__ embB,
              float* __restrict__ cbias, float* __restrict__ fb)
{
    __shared__ float sm[32 * 33];
    int id = blockIdx.x;
    if (id < 3072) {                 // qkv_w: z4, K512, N1536 (16x48)
        int z = id / 768, r = id % 768;
        packT_body(sm, qkv_w + (size_t)z * 512 * 1536, wcat + (size_t)z * 2048 * 512,
                   512, 1536, r % 16, r / 16);
    } else if (id < 4096) {          // gate_w: z4, K512, N512 (16x16)
        id -= 3072; int z = id / 256, r = id % 256;
        packT_body(sm, gate_w + (size_t)z * 512 * 512,
                   wcat + (size_t)z * 2048 * 512 + (size_t)1536 * 512,
                   512, 512, r % 16, r / 16);
    } else if (id < 8192) {          // mlp_w1: z4, K512, N2048 (16x64)
        id -= 4096; int z = id / 1024, r = id % 1024;
        packT_body(sm, mlp_w1 + (size_t)z * 512 * 2048, w1T + (size_t)z * 2048 * 512,
                   512, 2048, r % 16, r / 16);
    } else if (id < 12288) {         // mlp_w2: z4, K2048, N512 (64x16)
        id -= 8192; int z = id / 1024, r = id % 1024;
        packT_body(sm, mlp_w2 + (size_t)z * 2048 * 512, w2T + (size_t)z * 512 * 2048,
                   2048, 512, r % 64, r / 64);
    } else if (id < 12544) {         // hash_proj (16x16)
        id -= 12288;
        packT_body(sm, hash_proj, whashT, 512, 512, id % 16, id / 16);
    } else if (id < 12672) {         // head_w: K512, N256 (16x8)
        id -= 12544;
        packT_body(sm, head_w, hwT, 512, 256, id % 16, id / 16);
    } else if (id < 14720) {         // enc_w: z8, K512, N512 (16x16)
        id -= 12672; int z = id / 256, r = id % 256;
        packT_body(sm, enc_w + (size_t)z * 512 * 512, encT + (size_t)z * 512 * 512,
                   512, 512, r % 16, r / 16);
    } else if (id < 15744) {         // dec_w cast: 2097152 elems
        cast_body(dec_w, decb, id - 14720);
    } else if (id < 15808) {         // byte_emb cast: 131072 elems
        cast_body(byte_emb, embB, id - 15744);
    } else if (id < 15840) {         // catbias: 32 blocks
        id -= 15808;
        const int i = id >> 3;
        const int n = (id & 7) * 256 + threadIdx.x;
        cbias[i * 2048 + n] = (n < 1536) ? qkv_b[i * 1536 + n] : gate_b[i * 512 + n - 1536];
    } else {                         // fused decoder+head bias (1 block)
        const int o = threadIdx.x;
        float s = head_b[o];
        for (int d = 0; d < DIMD; d++) s = fmaf(dec_b[d], head_w[d * 256 + o], s);
        #pragma unroll
        for (int p = 0; p < PP; p++) fb[p * 256 + o] = s;
    }
}

// ---- LayerNorm: one wave per row, bf16 out ----
__global__ __launch_bounds__(256)
void ln_kernel(const float* __restrict__ x, const float* __restrict__ g,
               const float* __restrict__ b, unsigned short* __restrict__ h)
{
    const int row = blockIdx.x * 4 + (threadIdx.x >> 6);
    const int lane = threadIdx.x & 63;
    const float* xr = x + (long)row * DIMD;
    float4 v0 = *(const float4*)(xr + lane * 8);
    float4 v1 = *(const float4*)(xr + lane * 8 + 4);
    float xv[8] = {v0.x, v0.y, v0.z, v0.w, v1.x, v1.y, v1.z, v1.w};
    float s = 0.f, q = 0.f;
    #pragma unroll
    for (int j = 0; j < 8; j++) { s += xv[j]; q += xv[j] * xv[j]; }
    #pragma unroll
    for (int off = 1; off < 64; off <<= 1) {
        s += __shfl_xor(s, off);
        q += __shfl_xor(q, off);
    }
    const float mean = s * (1.f / DIMD);
    const float var  = q * (1.f / DIMD) - mean * mean;
    const float rstd = rsqrtf(var + 1e-5f);
    float4 g0 = *(const float4*)(g + lane * 8);
    float4 g1 = *(const float4*)(g + lane * 8 + 4);
    float4 b0 = *(const float4*)(b + lane * 8);
    float4 b1 = *(const float4*)(b + lane * 8 + 4);
    float gv[8] = {g0.x, g0.y, g0.z, g0.w, g1.x, g1.y, g1.z, g1.w};
    float bb[8] = {b0.x, b0.y, b0.z, b0.w, b1.x, b1.y, b1.z, b1.w};
    u16x8 o;
    #pragma unroll
    for (int j = 0; j < 8; j++) o[j] = f2bf((xv[j] - mean) * rstd * gv[j] + bb[j]);
    *reinterpret_cast<u16x8*>(h + (long)row * DIMD + lane * 8) = o;
}

// ---- fused embed+encode ----
__global__ __launch_bounds__(128)
void embed_kernel(const int* __restrict__ bytes, const float* __restrict__ E,
                  const float* __restrict__ enc_b, float* __restrict__ x0,
                  unsigned short* __restrict__ x0b)
{
    const int patch = blockIdx.x;
    __shared__ int by[PP];
    if (threadIdx.x < PP) by[threadIdx.x] = bytes[patch * PP + threadIdx.x];
    __syncthreads();
    const int o = threadIdx.x * 4;
    float4 acc = *(const float4*)(enc_b + o);
    #pragma unroll
    for (int p = 0; p < PP; p++) {
        float4 e = *(const float4*)(E + ((long)(p * 256 + by[p])) * DIMD + o);
        acc.x += e.x; acc.y += e.y; acc.z += e.z; acc.w += e.w;
    }
    *(float4*)(x0 + (long)patch * DIMD + o) = acc;
    u16x4 ob; ob[0] = f2bf(acc.x); ob[1] = f2bf(acc.y);
    ob[2] = f2bf(acc.z); ob[3] = f2bf(acc.w);
    *reinterpret_cast<u16x4*>(x0b + (long)patch * DIMD + o) = ob;
}

// ---- scan partial sums: 256 thr, 2 dims/thread, ushort2 loads ----
__global__ __launch_bounds__(256)
void scan_partial(const unsigned short* __restrict__ qg, float* __restrict__ S)
{
    const int b = blockIdx.x >> 6, c = blockIdx.x & 63, d2 = threadIdx.x * 2;
    const unsigned short* base = qg + (size_t)(b * LPATCH + c * CLEN) * QGS;
    float s0 = 0.f, s1 = 0.f;
    for (int l = 0; l < CLEN; l++) {
        ushort2 kk = *(const ushort2*)(base + l * QGS + DIMD + d2);
        ushort2 vv = *(const ushort2*)(base + l * QGS + 2 * DIMD + d2);
        s0 = fmaf(bf2f(kk.x), bf2f(vv.x), s0);
        s1 = fmaf(bf2f(kk.y), bf2f(vv.y), s1);
    }
    *(float2*)(S + (size_t)(b * NCHUNK + c) * DIMD + d2) = make_float2(s0, s1);
}

// ---- exclusive prefix over chunk sums: register-batched loads ----
// 16 blocks (4 b x 4 d-slices) x 128 threads. All 64 loads issued
// independently into registers (full unroll -> static indices), then the
// serial prefix runs on registers and stores stream out. Same add order
// as the old walker -> bit-identical.
__global__ __launch_bounds__(128)
void scan_prefix(float* __restrict__ S)
{
    const int b = blockIdx.x & 3;
    const int d = (blockIdx.x >> 2) * 128 + threadIdx.x;
    float* Sp = S + (size_t)b * NCHUNK * DIMD + d;
    float v[NCHUNK];
    #pragma unroll
    for (int c = 0; c < NCHUNK; c++) v[c] = Sp[(size_t)c * DIMD];
    float run = 0.f;
    #pragma unroll
    for (int c = 0; c < NCHUNK; c++) {
        Sp[(size_t)c * DIMD] = run;
        run += v[c];
    }
}

// ---- scan apply: 256 thr, 2 dims/thread ----
__global__ __launch_bounds__(256)
void scan_apply(const unsigned short* __restrict__ qg,
                const float* __restrict__ S, float* __restrict__ x)
{
    const int b = blockIdx.x >> 6, c = blockIdx.x & 63, d2 = threadIdx.x * 2;
    float2 kv = *(const float2*)(S + (size_t)(b * NCHUNK + c) * DIMD + d2);
    const int row0 = b * LPATCH + c * CLEN;
    for (int l = 0; l < CLEN; l++) {
        const unsigned short* qb = qg + (size_t)(row0 + l) * QGS;
        ushort2 qq = *(const ushort2*)(qb + d2);
        ushort2 kk = *(const ushort2*)(qb + DIMD + d2);
        ushort2 vv = *(const ushort2*)(qb + 2 * DIMD + d2);
        ushort2 gg = *(const ushort2*)(qb + 3 * DIMD + d2);
        kv.x = fmaf(bf2f(kk.x), bf2f(vv.x), kv.x);
        kv.y = fmaf(bf2f(kk.y), bf2f(vv.y), kv.y);
        const float sg0 = 1.f / (1.f + expf(-bf2f(gg.x)));
        const float sg1 = 1.f / (1.f + expf(-bf2f(gg.y)));
        float* xr = x + (size_t)(row0 + l) * DIMD;
        float2 xv = *(const float2*)(xr + d2);
        xv.x += bf2f(qq.x) * kv.x * sg0;
        xv.y += bf2f(qq.y) * kv.y * sg1;
        *(float2*)(xr + d2) = xv;
    }
}

extern "C" void kernel_launch(void* const* d_in, const int* in_sizes, int n_in,
                              void* d_out, int out_size, void* d_ws, size_t ws_size,
                              hipStream_t stream)
{
    (void)in_sizes; (void)n_in; (void)out_size; (void)ws_size;

    const int*   bytes_in  = (const int*)d_in[0];
    const float* byte_emb  = (const float*)d_in[1];
    const float* enc_w     = (const float*)d_in[2];
    const float* enc_b     = (const float*)d_in[3];
    const float* hash_proj = (const float*)d_in[4];
    const float* qkv_w     = (const float*)d_in[5];
    const float* qkv_b     = (const float*)d_in[6];
    const float* gate_w    = (const float*)d_in[7];
    const float* gate_b    = (const float*)d_in[8];
    const float* ln1_g     = (const float*)d_in[9];
    const float* ln1_b     = (const float*)d_in[10];
    const float* mlp_w1    = (const float*)d_in[11];
    const float* mlp_b1    = (const float*)d_in[12];
    const float* mlp_w2    = (const float*)d_in[13];
    const float* mlp_b2    = (const float*)d_in[14];
    const float* ln2_g     = (const float*)d_in[15];
    const float* ln2_b     = (const float*)d_in[16];
    const float* dec_w     = (const float*)d_in[17];
    const float* dec_b     = (const float*)d_in[18];
    const float* head_w    = (const float*)d_in[19];
    const float* head_b    = (const float*)d_in[20];
    float* out = (float*)d_out;

    // ---- workspace layout ----
    char* ws = (char*)d_ws;
    size_t o = 0;
    auto alloc = [&](size_t bytes) { char* p = ws + o; o += (bytes + 255) & ~(size_t)255; return p; };
    unsigned short* wcat   = (unsigned short*)alloc((size_t)4 * 2048 * 512 * 2);
    unsigned short* w1T    = (unsigned short*)alloc((size_t)4 * 2048 * 512 * 2);
    unsigned short* w2T    = (unsigned short*)alloc((size_t)4 * 512 * 2048 * 2);
    unsigned short* whashT = (unsigned short*)alloc((size_t)512 * 512 * 2);
    unsigned short* wWfT   = (unsigned short*)alloc((size_t)2048 * 512 * 2);
    unsigned short* encT   = (unsigned short*)alloc((size_t)8 * 512 * 512 * 2);
    unsigned short* hwT    = (unsigned short*)alloc((size_t)256 * 512 * 2);
    unsigned short* decb   = (unsigned short*)alloc((size_t)512 * 8 * 512 * 2);
    unsigned short* embB   = (unsigned short*)alloc((size_t)256 * 512 * 2);
    float* cbias           = (float*)alloc((size_t)4 * 2048 * 4);
    float* fb              = (float*)alloc(2048 * 4);
    float* E               = (float*)alloc((size_t)8 * 256 * 512 * 4);
    float* x               = (float*)alloc((size_t)MROWS * DIMD * 4);
    float* x0              = (float*)alloc((size_t)MROWS * DIMD * 4);
    unsigned short* x0b    = (unsigned short*)alloc((size_t)MROWS * DIMD * 2);
    unsigned short* h      = (unsigned short*)alloc((size_t)MROWS * DIMD * 2);
    unsigned short* xb     = (unsigned short*)alloc((size_t)MROWS * DIMD * 2);
    float* S               = (float*)alloc((size_t)BBATCH * NCHUNK * DIMD * 4);
    unsigned short* qg     = (unsigned short*)alloc((size_t)MROWS * 2048 * 2);
    unsigned short* hid    = (unsigned short*)alloc((size_t)MROWS * 2048 * 2);

    // ---- 1. all weight preprocessing (incl. fused decoder+head bias) ----
    megapack<<<dim3(15841), 256, 0, stream>>>(
        qkv_w, gate_w, mlp_w1, mlp_w2, hash_proj, head_w, enc_w, dec_w, byte_emb,
        qkv_b, gate_b, dec_b, head_b,
        wcat, w1T, w2T, whashT, hwT, encT, decb, embB, cbias, fb);

    // ---- 2. WfT[p*256+o][d] = sum_c head_wT[o][c] * dec_w[d][p][c] ----
    mfma_gemm<64, 0, false, false, true><<<dim3(4, 4, 8), 256, 0, stream>>>(
        hwT, 512, 0L, decb, PP * 512, 512L,
        nullptr, nullptr, 0, wWfT, 512, (long)256 * 512, 512);

    // ---- 3. E[p] = byte_emb @ enc_w[p] ----
    mfma_gemm<64, 0, false, false, false><<<dim3(4, 4, 8), 256, 0, stream>>>(
        embB, 512, 0L, encT, 512, (long)512 * 512,
        nullptr, nullptr, 0, E, 512, (long)256 * 512, 512);

    embed_kernel<<<dim3(MROWS), dim3(128), 0, stream>>>(bytes_in, E, enc_b, x0, x0b);

    // ---- 4. x = x0 + tanh(x0 @ hash_proj) ----
    mfma_gemm<64, 1, false, true, false><<<dim3(MROWS / 64, 4, 1), 256, 0, stream>>>(
        x0b, DIMD, 0L, whashT, DIMD, 0L, nullptr, x0, DIMD, x, DIMD, 0L, DIMD);

    for (int i = 0; i < NLAYER; i++) {
        ln_kernel<<<dim3(MROWS / 4), 256, 0, stream>>>(x, ln1_g + i * DIMD, ln1_b + i * DIMD, h);
        mfma_gemm<64, 0, true, false, true><<<dim3(MROWS / 64, 16, 1), 256, 0, stream>>>(
            h, DIMD, 0L, wcat + (size_t)i * 2048 * 512, DIMD, 0L,
            cbias + (size_t)i * 2048, nullptr, 0, qg, 2048, 0L, DIMD);
        scan_partial<<<dim3(BBATCH * NCHUNK), 256, 0, stream>>>(qg, S);
        scan_prefix<<<dim3(16), dim3(128), 0, stream>>>(S);
        scan_apply<<<dim3(BBATCH * NCHUNK), 256, 0, stream>>>(qg, S, x);
        ln_kernel<<<dim3(MROWS / 4), 256, 0, stream>>>(x, ln2_g + i * DIMD, ln2_b + i * DIMD, h);
        mfma_gemm<64, 2, true, false, true><<<dim3(MROWS / 64, 16, 1), 256, 0, stream>>>(
            h, DIMD, 0L, w1T + (size_t)i * 2048 * 512, DIMD, 0L,
            mlp_b1 + (size_t)i * 2048, nullptr, 0, hid, 2048, 0L, DIMD);
        if (i < NLAYER - 1) {
            mfma_gemm<64, 0, true, true, false><<<dim3(MROWS / 64, 4, 1), 256, 0, stream>>>(
                hid, 2048, 0L, w2T + (size_t)i * 512 * 2048, 2048, 0L,
                mlp_b2 + (size_t)i * DIMD, x, DIMD, x, DIMD, 0L, 2048);
        } else {
            mfma_gemm<64, 0, true, true, true><<<dim3(MROWS / 64, 4, 1), 256, 0, stream>>>(
                hid, 2048, 0L, w2T + (size_t)i * 512 * 2048, 2048, 0L,
                mlp_b2 + (size_t)i * DIMD, x, DIMD, xb, DIMD, 0L, 2048);
        }
    }

    // ---- head ----
    mfma_gemm<64, 0, true, false, false><<<dim3(MROWS / 64, 16, 1), 256, 0, stream>>>(
        xb, DIMD, 0L, wWfT, DIMD, 0L, fb, nullptr, 0, out, 2048, 0L, DIMD);
}

// Round 14
// 465.677 us; speedup vs baseline: 1.1109x; 1.0074x over previous
//
#include <hip/hip_runtime.h>
#include <hip/hip_bf16.h>
#include <math.h>

#define DIMD 512
#define NLAYER 4
#define PP 8
#define BBATCH 4
#define LBYTES 8192
#define LPATCH 1024
#define MROWS (BBATCH * LPATCH)   // 4096

#define NCHUNK 64
#define CLEN   16
#define QGS    (4 * DIMD)   // 2048

typedef __bf16 bf16x8 __attribute__((ext_vector_type(8)));
typedef float f32x4 __attribute__((ext_vector_type(4)));
typedef unsigned short u16x4 __attribute__((ext_vector_type(4)));
typedef unsigned short u16x8 __attribute__((ext_vector_type(8)));

__device__ __forceinline__ unsigned short f2bf(float f) {
    union { float f; unsigned u; } v; v.f = f;
    unsigned r = v.u + 0x7FFFu + ((v.u >> 16) & 1u);   // RNE
    return (unsigned short)(r >> 16);
}
__device__ __forceinline__ float bf2f(unsigned short u) {
    union { unsigned u; float f; } v; v.u = ((unsigned)u) << 16;
    return v.f;
}

__device__ __forceinline__ void glds16(const unsigned short* g, unsigned short* l) {
    __builtin_amdgcn_global_load_lds((__attribute__((address_space(1))) void*)g,
                                     (__attribute__((address_space(3))) void*)l,
                                     16, 0, 0);
}

// =======================================================================
// bf16 MFMA GEMM (NT): C[M,N] = act(A[M,K] @ Bt[N,K]^T + bias) (+res)
// (R5-proven structure — do not touch)
// =======================================================================
template<int TM, int ACT, bool BIAS, bool RES, bool OBF>
__global__ __launch_bounds__(256)
void mfma_gemm(const unsigned short* __restrict__ A, int lda, long aZ,
               const unsigned short* __restrict__ Bt, int ldb, long bZ,
               const float* __restrict__ bias,
               const float* __restrict__ res, int ldr,
               void* __restrict__ Cv, int ldc, long cZ, int K)
{
    constexpr int M_REP = TM / 32;
    __shared__ unsigned short As[TM * 32];
    __shared__ unsigned short Bs[128 * 32];

    const int tid = threadIdx.x;
    const int w = tid >> 6, l = tid & 63;
    const int row0 = blockIdx.x * TM;
    const int col0 = blockIdx.y * 128;
    A  += (size_t)blockIdx.z * aZ;
    Bt += (size_t)blockIdx.z * bZ;
    unsigned short* Cb = (unsigned short*)Cv + (size_t)blockIdx.z * cZ;
    float*          Cf = (float*)Cv          + (size_t)blockIdx.z * cZ;

    const int cA = w * 64 + l;
    const unsigned short* gA0 = A + (size_t)(row0 + (cA >> 2)) * lda + (cA & 3) * 8;
    const unsigned short* gB0 = Bt + (size_t)(col0 + (cA >> 2)) * ldb + (cA & 3) * 8;
    const unsigned short* gB1 = Bt + (size_t)(col0 + 64 + (cA >> 2)) * ldb + (cA & 3) * 8;
    unsigned short* lA0 = &As[w * 512];
    unsigned short* lB0 = &Bs[w * 512];
    unsigned short* lB1 = &Bs[2048 + w * 512];
    const unsigned short* gA1 = nullptr;
    unsigned short* lA1 = nullptr;
    if constexpr (TM == 128) {
        gA1 = A + (size_t)(row0 + 64 + (cA >> 2)) * lda + (cA & 3) * 8;
        lA1 = &As[2048 + w * 512];
    }

    const int wr = (w >> 1) * (TM / 2);
    const int wc = (w & 1) * 64;
    const int lr = l & 15, lk = (l >> 4) * 8;
    const int aBase = (wr + lr) * 32 + lk;
    const int bBase = (wc + lr) * 32 + lk;

    f32x4 acc[M_REP][4] = {};

    for (int k0 = 0; k0 < K; k0 += 32) {
        glds16(gA0, lA0);  gA0 += 32;
        if constexpr (TM == 128) { glds16(gA1, lA1); gA1 += 32; }
        glds16(gB0, lB0);  gB0 += 32;
        glds16(gB1, lB1);  gB1 += 32;
        __syncthreads();
        bf16x8 af[M_REP], bfr[4];
        #pragma unroll
        for (int m = 0; m < M_REP; m++)
            af[m] = *reinterpret_cast<const bf16x8*>(&As[aBase + m * 512]);
        #pragma unroll
        for (int n = 0; n < 4; n++)
            bfr[n] = *reinterpret_cast<const bf16x8*>(&Bs[bBase + n * 512]);
        #pragma unroll
        for (int m = 0; m < M_REP; m++)
            #pragma unroll
            for (int n = 0; n < 4; n++)
                acc[m][n] = __builtin_amdgcn_mfma_f32_16x16x32_bf16(
                    af[m], bfr[n], acc[m][n], 0, 0, 0);
        __syncthreads();
    }

    const int r0 = row0 + wr + (l >> 4) * 4;
    const int c0 = col0 + wc + lr;
    float bv[4] = {0.f, 0.f, 0.f, 0.f};
    if (BIAS) {
        #pragma unroll
        for (int n = 0; n < 4; n++) bv[n] = bias[c0 + n * 16];
    }
    #pragma unroll
    for (int m = 0; m < M_REP; m++) {
        #pragma unroll
        for (int j = 0; j < 4; j++) {
            const int row = r0 + m * 16 + j;
            #pragma unroll
            for (int n = 0; n < 4; n++) {
                float v = acc[m][n][j];
                if (BIAS) v += bv[n];
                if (ACT == 1) v = tanhf(v);
                if (ACT == 2) v = 0.5f * v * (1.f + erff(v * 0.70710678118f));
                if (RES) v += res[(size_t)row * ldr + c0 + n * 16];
                if (OBF) Cb[(size_t)row * ldc + c0 + n * 16] = f2bf(v);
                else     Cf[(size_t)row * ldc + c0 + n * 16] = v;
            }
        }
    }
}

// ======================= megapack: all weight preprocessing =======================
__device__ __forceinline__ void packT_body(float* sm, const float* __restrict__ in,
                                           unsigned short* __restrict__ out,
                                           int K, int N, int bx, int by)
{
    float (*t)[33] = (float(*)[33])sm;
    const int k0 = bx * 32, n0 = by * 32;
    const int tx = threadIdx.x & 31, ty = threadIdx.x >> 5;
    #pragma unroll
    for (int i = 0; i < 4; i++)
        t[ty + i * 8][tx] = in[(size_t)(k0 + ty + i * 8) * N + n0 + tx];
    __syncthreads();
    #pragma unroll
    for (int i = 0; i < 4; i++)
        out[(size_t)(n0 + ty + i * 8) * K + k0 + tx] = f2bf(t[tx][ty + i * 8]);
}

__device__ __forceinline__ void cast_body(const float* __restrict__ in,
                                          unsigned short* __restrict__ out, int blk)
{
    const long i = ((long)blk * 256 + threadIdx.x) * 8;
    float4 a = *(const float4*)(in + i);
    float4 b = *(const float4*)(in + i + 4);
    u16x8 o;
    o[0] = f2bf(a.x); o[1] = f2bf(a.y); o[2] = f2bf(a.z); o[3] = f2bf(a.w);
    o[4] = f2bf(b.x); o[5] = f2bf(b.y); o[6] = f2bf(b.z); o[7] = f2bf(b.w);
    *reinterpret_cast<u16x8*>(out + i) = o;
}

__global__ __launch_bounds__(256)
void megapack(const float* __restrict__ qkv_w, const float* __restrict__ gate_w,
              const float* __restrict__ mlp_w1, const float* __restrict__ mlp_w2,
              const float* __restrict__ hash_proj, const float* __restrict__ head_w,
              const float* __restrict__ enc_w, const float* __restrict__ dec_w,
              const float* __restrict__ byte_emb,
              const float* __restrict__ qkv_b, const float* __restrict__ gate_b,
              const float* __restrict__ dec_b, const float* __restrict__ head_b,
              unsigned short* __restrict__ wcat, unsigned short* __restrict__ w1T,
              unsigned short* __restrict__ w2T, unsigned short* __restrict__ whashT,
              unsigned short* __restrict__ hwT, unsigned short* __restrict__ encT,
              unsigned short* __restrict__ decb, unsigned short* __restrict__ embB,
              float* __restrict__ cbias, float* __restrict__ fb)
{
    __shared__ float sm[32 * 33];
    int id = blockIdx.x;
    if (id < 3072) {                 // qkv_w: z4, K512, N1536 (16x48)
        int z = id / 768, r = id % 768;
        packT_body(sm, qkv_w + (size_t)z * 512 * 1536, wcat + (size_t)z * 2048 * 512,
                   512, 1536, r % 16, r / 16);
    } else if (id < 4096) {          // gate_w: z4, K512, N512 (16x16)
        id -= 3072; int z = id / 256, r = id % 256;
        packT_body(sm, gate_w + (size_t)z * 512 * 512,
                   wcat + (size_t)z * 2048 * 512 + (size_t)1536 * 512,
                   512, 512, r % 16, r / 16);
    } else if (id < 8192) {          // mlp_w1: z4, K512, N2048 (16x64)
        id -= 4096; int z = id / 1024, r = id % 1024;
        packT_body(sm, mlp_w1 + (size_t)z * 512 * 2048, w1T + (size_t)z * 2048 * 512,
                   512, 2048, r % 16, r / 16);
    } else if (id < 12288) {         // mlp_w2: z4, K2048, N512 (64x16)
        id -= 8192; int z = id / 1024, r = id % 1024;
        packT_body(sm, mlp_w2 + (size_t)z * 2048 * 512, w2T + (size_t)z * 512 * 2048,
                   2048, 512, r % 64, r / 64);
    } else if (id < 12544) {         // hash_proj (16x16)
        id -= 12288;
        packT_body(sm, hash_proj, whashT, 512, 512, id % 16, id / 16);
    } else if (id < 12672) {         // head_w: K512, N256 (16x8)
        id -= 12544;
        packT_body(sm, head_w, hwT, 512, 256, id % 16, id / 16);
    } else if (id < 14720) {         // enc_w: z8, K512, N512 (16x16)
        id -= 12672; int z = id / 256, r = id % 256;
        packT_body(sm, enc_w + (size_t)z * 512 * 512, encT + (size_t)z * 512 * 512,
                   512, 512, r % 16, r / 16);
    } else if (id < 15744) {         // dec_w cast: 2097152 elems
        cast_body(dec_w, decb, id - 14720);
    } else if (id < 15808) {         // byte_emb cast: 131072 elems
        cast_body(byte_emb, embB, id - 15744);
    } else if (id < 15840) {         // catbias: 32 blocks
        id -= 15808;
        const int i = id >> 3;
        const int n = (id & 7) * 256 + threadIdx.x;
        cbias[i * 2048 + n] = (n < 1536) ? qkv_b[i * 1536 + n] : gate_b[i * 512 + n - 1536];
    } else {                         // fused decoder+head bias (1 block)
        const int o = threadIdx.x;
        float s = head_b[o];
        for (int d = 0; d < DIMD; d++) s = fmaf(dec_b[d], head_w[d * 256 + o], s);
        #pragma unroll
        for (int p = 0; p < PP; p++) fb[p * 256 + o] = s;
    }
}

// ---- LayerNorm (ln1): one wave per row, bf16 out ----
__global__ __launch_bounds__(256)
void ln_kernel(const float* __restrict__ x, const float* __restrict__ g,
               const float* __restrict__ b, unsigned short* __restrict__ h)
{
    const int row = blockIdx.x * 4 + (threadIdx.x >> 6);
    const int lane = threadIdx.x & 63;
    const float* xr = x + (long)row * DIMD;
    float4 v0 = *(const float4*)(xr + lane * 8);
    float4 v1 = *(const float4*)(xr + lane * 8 + 4);
    float xv[8] = {v0.x, v0.y, v0.z, v0.w, v1.x, v1.y, v1.z, v1.w};
    float s = 0.f, q = 0.f;
    #pragma unroll
    for (int j = 0; j < 8; j++) { s += xv[j]; q += xv[j] * xv[j]; }
    #pragma unroll
    for (int off = 1; off < 64; off <<= 1) {
        s += __shfl_xor(s, off);
        q += __shfl_xor(q, off);
    }
    const float mean = s * (1.f / DIMD);
    const float var  = q * (1.f / DIMD) - mean * mean;
    const float rstd = rsqrtf(var + 1e-5f);
    float4 g0 = *(const float4*)(g + lane * 8);
    float4 g1 = *(const float4*)(g + lane * 8 + 4);
    float4 b0 = *(const float4*)(b + lane * 8);
    float4 b1 = *(const float4*)(b + lane * 8 + 4);
    float gv[8] = {g0.x, g0.y, g0.z, g0.w, g1.x, g1.y, g1.z, g1.w};
    float bb[8] = {b0.x, b0.y, b0.z, b0.w, b1.x, b1.y, b1.z, b1.w};
    u16x8 o;
    #pragma unroll
    for (int j = 0; j < 8; j++) o[j] = f2bf((xv[j] - mean) * rstd * gv[j] + bb[j]);
    *reinterpret_cast<u16x8*>(h + (long)row * DIMD + lane * 8) = o;
}

// ---- fused embed+encode ----
__global__ __launch_bounds__(128)
void embed_kernel(const int* __restrict__ bytes, const float* __restrict__ E,
                  const float* __restrict__ enc_b, float* __restrict__ x0,
                  unsigned short* __restrict__ x0b)
{
    const int patch = blockIdx.x;
    __shared__ int by[PP];
    if (threadIdx.x < PP) by[threadIdx.x] = bytes[patch * PP + threadIdx.x];
    __syncthreads();
    const int o = threadIdx.x * 4;
    float4 acc = *(const float4*)(enc_b + o);
    #pragma unroll
    for (int p = 0; p < PP; p++) {
        float4 e = *(const float4*)(E + ((long)(p * 256 + by[p])) * DIMD + o);
        acc.x += e.x; acc.y += e.y; acc.z += e.z; acc.w += e.w;
    }
    *(float4*)(x0 + (long)patch * DIMD + o) = acc;
    u16x4 ob; ob[0] = f2bf(acc.x); ob[1] = f2bf(acc.y);
    ob[2] = f2bf(acc.z); ob[3] = f2bf(acc.w);
    *reinterpret_cast<u16x4*>(x0b + (long)patch * DIMD + o) = ob;
}

// ---- scan partial sums: 256 thr, 2 dims/thread, ushort2 loads ----
__global__ __launch_bounds__(256)
void scan_partial(const unsigned short* __restrict__ qg, float* __restrict__ S)
{
    const int b = blockIdx.x >> 6, c = blockIdx.x & 63, d2 = threadIdx.x * 2;
    const unsigned short* base = qg + (size_t)(b * LPATCH + c * CLEN) * QGS;
    float s0 = 0.f, s1 = 0.f;
    for (int l = 0; l < CLEN; l++) {
        ushort2 kk = *(const ushort2*)(base + l * QGS + DIMD + d2);
        ushort2 vv = *(const ushort2*)(base + l * QGS + 2 * DIMD + d2);
        s0 = fmaf(bf2f(kk.x), bf2f(vv.x), s0);
        s1 = fmaf(bf2f(kk.y), bf2f(vv.y), s1);
    }
    *(float2*)(S + (size_t)(b * NCHUNK + c) * DIMD + d2) = make_float2(s0, s1);
}

// ---- exclusive prefix over chunk sums: register-batched loads ----
__global__ __launch_bounds__(128)
void scan_prefix(float* __restrict__ S)
{
    const int b = blockIdx.x & 3;
    const int d = (blockIdx.x >> 2) * 128 + threadIdx.x;
    float* Sp = S + (size_t)b * NCHUNK * DIMD + d;
    float v[NCHUNK];
    #pragma unroll
    for (int c = 0; c < NCHUNK; c++) v[c] = Sp[(size_t)c * DIMD];
    float run = 0.f;
    #pragma unroll
    for (int c = 0; c < NCHUNK; c++) {
        Sp[(size_t)c * DIMD] = run;
        run += v[c];
    }
}

// ---- fused scan apply + residual + LN2 (barrier-free: wave owns 2 full rows) ----
// 512 thr = 8 waves; wave w handles rows [2w, 2w+2) of its 16-row chunk.
// S holds the EXCLUSIVE PREFIX (scan_prefix ran). Wave redundantly
// accumulates k*v over its preceding <=14 rows — wave-local, zero
// __syncthreads. LN reduce = 64-lane shfl (8 dims/lane). (K8-proven.)
__global__ __launch_bounds__(512)
void scan_apply_ln(const unsigned short* __restrict__ qg,
                   const float* __restrict__ S, float* __restrict__ x,
                   const float* __restrict__ lg, const float* __restrict__ lb,
                   unsigned short* __restrict__ h)
{
    const int b = blockIdx.x >> 6, c = blockIdx.x & 63;
    const int w = threadIdx.x >> 6, lane = threadIdx.x & 63;
    const int d0 = lane * 8;

    float kv[8];
    {
        const float* Sp = S + (size_t)(b * NCHUNK + c) * DIMD + d0;
        float4 a = *(const float4*)Sp;
        float4 bq = *(const float4*)(Sp + 4);
        kv[0] = a.x; kv[1] = a.y; kv[2] = a.z; kv[3] = a.w;
        kv[4] = bq.x; kv[5] = bq.y; kv[6] = bq.z; kv[7] = bq.w;
    }
    const int row0 = b * LPATCH + c * CLEN;
    for (int l = 0; l < 2 * w; l++) {
        const unsigned short* qb = qg + (size_t)(row0 + l) * QGS;
        u16x8 kk = *reinterpret_cast<const u16x8*>(qb + DIMD + d0);
        u16x8 vv = *reinterpret_cast<const u16x8*>(qb + 2 * DIMD + d0);
        #pragma unroll
        for (int j = 0; j < 8; j++) kv[j] = fmaf(bf2f(kk[j]), bf2f(vv[j]), kv[j]);
    }

    float gv[8], bv[8];
    {
        float4 g0 = *(const float4*)(lg + d0);
        float4 g1 = *(const float4*)(lg + d0 + 4);
        float4 b0 = *(const float4*)(lb + d0);
        float4 b1 = *(const float4*)(lb + d0 + 4);
        gv[0] = g0.x; gv[1] = g0.y; gv[2] = g0.z; gv[3] = g0.w;
        gv[4] = g1.x; gv[5] = g1.y; gv[6] = g1.z; gv[7] = g1.w;
        bv[0] = b0.x; bv[1] = b0.y; bv[2] = b0.z; bv[3] = b0.w;
        bv[4] = b1.x; bv[5] = b1.y; bv[6] = b1.z; bv[7] = b1.w;
    }

    for (int l = 2 * w; l < 2 * w + 2; l++) {
        const unsigned short* qb = qg + (size_t)(row0 + l) * QGS;
        u16x8 qq = *reinterpret_cast<const u16x8*>(qb + d0);
        u16x8 kk = *reinterpret_cast<const u16x8*>(qb + DIMD + d0);
        u16x8 vv = *reinterpret_cast<const u16x8*>(qb + 2 * DIMD + d0);
        u16x8 gg = *reinterpret_cast<const u16x8*>(qb + 3 * DIMD + d0);
        float* xr = x + (size_t)(row0 + l) * DIMD + d0;
        float4 xv0 = *(const float4*)xr;
        float4 xv1 = *(const float4*)(xr + 4);
        float xold[8] = {xv0.x, xv0.y, xv0.z, xv0.w, xv1.x, xv1.y, xv1.z, xv1.w};
        float xn[8];
        float s = 0.f, qs = 0.f;
        #pragma unroll
        for (int j = 0; j < 8; j++) {
            kv[j] = fmaf(bf2f(kk[j]), bf2f(vv[j]), kv[j]);
            const float sg = 1.f / (1.f + expf(-bf2f(gg[j])));
            const float nv = xold[j] + bf2f(qq[j]) * kv[j] * sg;
            xn[j] = nv; s += nv; qs += nv * nv;
        }
        *(float4*)xr       = make_float4(xn[0], xn[1], xn[2], xn[3]);
        *(float4*)(xr + 4) = make_float4(xn[4], xn[5], xn[6], xn[7]);
        #pragma unroll
        for (int off = 1; off < 64; off <<= 1) {
            s += __shfl_xor(s, off);
            qs += __shfl_xor(qs, off);
        }
        const float mean = s * (1.f / DIMD);
        const float var  = qs * (1.f / DIMD) - mean * mean;
        const float rstd = rsqrtf(var + 1e-5f);
        u16x8 ho;
        #pragma unroll
        for (int j = 0; j < 8; j++) ho[j] = f2bf((xn[j] - mean) * rstd * gv[j] + bv[j]);
        *reinterpret_cast<u16x8*>(h + (size_t)(row0 + l) * DIMD + d0) = ho;
    }
}

extern "C" void kernel_launch(void* const* d_in, const int* in_sizes, int n_in,
                              void* d_out, int out_size, void* d_ws, size_t ws_size,
                              hipStream_t stream)
{
    (void)in_sizes; (void)n_in; (void)out_size; (void)ws_size;

    const int*   bytes_in  = (const int*)d_in[0];
    const float* byte_emb  = (const float*)d_in[1];
    const float* enc_w     = (const float*)d_in[2];
    const float* enc_b     = (const float*)d_in[3];
    const float* hash_proj = (const float*)d_in[4];
    const float* qkv_w     = (const float*)d_in[5];
    const float* qkv_b     = (const float*)d_in[6];
    const float* gate_w    = (const float*)d_in[7];
    const float* gate_b    = (const float*)d_in[8];
    const float* ln1_g     = (const float*)d_in[9];
    const float* ln1_b     = (const float*)d_in[10];
    const float* mlp_w1    = (const float*)d_in[11];
    const float* mlp_b1    = (const float*)d_in[12];
    const float* mlp_w2    = (const float*)d_in[13];
    const float* mlp_b2    = (const float*)d_in[14];
    const float* ln2_g     = (const float*)d_in[15];
    const float* ln2_b     = (const float*)d_in[16];
    const float* dec_w     = (const float*)d_in[17];
    const float* dec_b     = (const float*)d_in[18];
    const float* head_w    = (const float*)d_in[19];
    const float* head_b    = (const float*)d_in[20];
    float* out = (float*)d_out;

    // ---- workspace layout ----
    char* ws = (char*)d_ws;
    size_t o = 0;
    auto alloc = [&](size_t bytes) { char* p = ws + o; o += (bytes + 255) & ~(size_t)255; return p; };
    unsigned short* wcat   = (unsigned short*)alloc((size_t)4 * 2048 * 512 * 2);
    unsigned short* w1T    = (unsigned short*)alloc((size_t)4 * 2048 * 512 * 2);
    unsigned short* w2T    = (unsigned short*)alloc((size_t)4 * 512 * 2048 * 2);
    unsigned short* whashT = (unsigned short*)alloc((size_t)512 * 512 * 2);
    unsigned short* wWfT   = (unsigned short*)alloc((size_t)2048 * 512 * 2);
    unsigned short* encT   = (unsigned short*)alloc((size_t)8 * 512 * 512 * 2);
    unsigned short* hwT    = (unsigned short*)alloc((size_t)256 * 512 * 2);
    unsigned short* decb   = (unsigned short*)alloc((size_t)512 * 8 * 512 * 2);
    unsigned short* embB   = (unsigned short*)alloc((size_t)256 * 512 * 2);
    float* cbias           = (float*)alloc((size_t)4 * 2048 * 4);
    float* fb              = (float*)alloc(2048 * 4);
    float* E               = (float*)alloc((size_t)8 * 256 * 512 * 4);
    float* x               = (float*)alloc((size_t)MROWS * DIMD * 4);
    float* x0              = (float*)alloc((size_t)MROWS * DIMD * 4);
    unsigned short* x0b    = (unsigned short*)alloc((size_t)MROWS * DIMD * 2);
    unsigned short* h      = (unsigned short*)alloc((size_t)MROWS * DIMD * 2);
    unsigned short* xb     = (unsigned short*)alloc((size_t)MROWS * DIMD * 2);
    float* S               = (float*)alloc((size_t)BBATCH * NCHUNK * DIMD * 4);
    unsigned short* qg     = (unsigned short*)alloc((size_t)MROWS * 2048 * 2);
    unsigned short* hid    = (unsigned short*)alloc((size_t)MROWS * 2048 * 2);

    // ---- 1. all weight preprocessing (incl. fused decoder+head bias) ----
    megapack<<<dim3(15841), 256, 0, stream>>>(
        qkv_w, gate_w, mlp_w1, mlp_w2, hash_proj, head_w, enc_w, dec_w, byte_emb,
        qkv_b, gate_b, dec_b, head_b,
        wcat, w1T, w2T, whashT, hwT, encT, decb, embB, cbias, fb);

    // ---- 2. WfT[p*256+o][d] = sum_c head_wT[o][c] * dec_w[d][p][c] ----
    mfma_gemm<64, 0, false, false, true><<<dim3(4, 4, 8), 256, 0, stream>>>(
        hwT, 512, 0L, decb, PP * 512, 512L,
        nullptr, nullptr, 0, wWfT, 512, (long)256 * 512, 512);

    // ---- 3. E[p] = byte_emb @ enc_w[p] ----
    mfma_gemm<64, 0, false, false, false><<<dim3(4, 4, 8), 256, 0, stream>>>(
        embB, 512, 0L, encT, 512, (long)512 * 512,
        nullptr, nullptr, 0, E, 512, (long)256 * 512, 512);

    embed_kernel<<<dim3(MROWS), dim3(128), 0, stream>>>(bytes_in, E, enc_b, x0, x0b);

    // ---- 4. x = x0 + tanh(x0 @ hash_proj) ----
    mfma_gemm<64, 1, false, true, false><<<dim3(MROWS / 64, 4, 1), 256, 0, stream>>>(
        x0b, DIMD, 0L, whashT, DIMD, 0L, nullptr, x0, DIMD, x, DIMD, 0L, DIMD);

    for (int i = 0; i < NLAYER; i++) {
        ln_kernel<<<dim3(MROWS / 4), 256, 0, stream>>>(x, ln1_g + i * DIMD, ln1_b + i * DIMD, h);
        mfma_gemm<64, 0, true, false, true><<<dim3(MROWS / 64, 16, 1), 256, 0, stream>>>(
            h, DIMD, 0L, wcat + (size_t)i * 2048 * 512, DIMD, 0L,
            cbias + (size_t)i * 2048, nullptr, 0, qg, 2048, 0L, DIMD);
        scan_partial<<<dim3(BBATCH * NCHUNK), 256, 0, stream>>>(qg, S);
        scan_prefix<<<dim3(16), dim3(128), 0, stream>>>(S);
        scan_apply_ln<<<dim3(BBATCH * NCHUNK), dim3(512), 0, stream>>>(
            qg, S, x, ln2_g + i * DIMD, ln2_b + i * DIMD, h);
        mfma_gemm<64, 2, true, false, true><<<dim3(MROWS / 64, 16, 1), 256, 0, stream>>>(
            h, DIMD, 0L, w1T + (size_t)i * 2048 * 512, DIMD, 0L,
            mlp_b1 + (size_t)i * 2048, nullptr, 0, hid, 2048, 0L, DIMD);
        if (i < NLAYER - 1) {
            mfma_gemm<64, 0, true, true, false><<<dim3(MROWS / 64, 4, 1), 256, 0, stream>>>(
                hid, 2048, 0L, w2T + (size_t)i * 512 * 2048, 2048, 0L,
                mlp_b2 + (size_t)i * DIMD, x, DIMD, x, DIMD, 0L, 2048);
        } else {
            mfma_gemm<64, 0, true, true, true><<<dim3(MROWS / 64, 4, 1), 256, 0, stream>>>(
                hid, 2048, 0L, w2T + (size_t)i * 512 * 2048, 2048, 0L,
                mlp_b2 + (size_t)i * DIMD, x, DIMD, xb, DIMD, 0L, 2048);
        }
    }

    // ---- head ----
    mfma_gemm<64, 0, true, false, false><<<dim3(MROWS / 64, 16, 1), 256, 0, stream>>>(
        xb, DIMD, 0L, wWfT, DIMD, 0L, fb, nullptr, 0, out, 2048, 0L, DIMD);
}

// Round 15
// 440.168 us; speedup vs baseline: 1.1753x; 1.0580x over previous
//
#include <hip/hip_runtime.h>
#include <hip/hip_bf16.h>
#include <math.h>

#define DIMD 512
#define NLAYER 4
#define PP 8
#define BBATCH 4
#define LBYTES 8192
#define LPATCH 1024
#define MROWS (BBATCH * LPATCH)   // 4096

#define NCHUNK 64
#define CLEN   16
#define QGS    (4 * DIMD)   // 2048

typedef __bf16 bf16x8 __attribute__((ext_vector_type(8)));
typedef float f32x4 __attribute__((ext_vector_type(4)));
typedef unsigned short u16x4 __attribute__((ext_vector_type(4)));
typedef unsigned short u16x8 __attribute__((ext_vector_type(8)));

__device__ __forceinline__ unsigned short f2bf(float f) {
    union { float f; unsigned u; } v; v.f = f;
    unsigned r = v.u + 0x7FFFu + ((v.u >> 16) & 1u);   // RNE
    return (unsigned short)(r >> 16);
}
__device__ __forceinline__ float bf2f(unsigned short u) {
    union { unsigned u; float f; } v; v.u = ((unsigned)u) << 16;
    return v.f;
}

__device__ __forceinline__ void glds16(const unsigned short* g, unsigned short* l) {
    __builtin_amdgcn_global_load_lds((__attribute__((address_space(1))) void*)g,
                                     (__attribute__((address_space(3))) void*)l,
                                     16, 0, 0);
}

// =======================================================================
// bf16 MFMA GEMM (NT): C[M,N] = act(A[M,K] @ Bt[N,K]^T + bias) (+res)
// BN=128: R5-proven 2x2-wave layout (byte-identical codegen to K14).
// BN=64:  4 waves stacked over M (wr=w*TM/4, wc=0) — doubles grid for
//         N=512 GEMMs (occupancy). Same K-accum order -> bit-identical.
// =======================================================================
template<int TM, int BN, int ACT, bool BIAS, bool RES, bool OBF>
__global__ __launch_bounds__(256)
void mfma_gemm(const unsigned short* __restrict__ A, int lda, long aZ,
               const unsigned short* __restrict__ Bt, int ldb, long bZ,
               const float* __restrict__ bias,
               const float* __restrict__ res, int ldr,
               void* __restrict__ Cv, int ldc, long cZ, int K)
{
    constexpr int M_REP = (BN == 128) ? TM / 32 : TM / 64;
    __shared__ unsigned short As[TM * 32];
    __shared__ unsigned short Bs[BN * 32];

    const int tid = threadIdx.x;
    const int w = tid >> 6, l = tid & 63;
    const int row0 = blockIdx.x * TM;
    const int col0 = blockIdx.y * BN;
    A  += (size_t)blockIdx.z * aZ;
    Bt += (size_t)blockIdx.z * bZ;
    unsigned short* Cb = (unsigned short*)Cv + (size_t)blockIdx.z * cZ;
    float*          Cf = (float*)Cv          + (size_t)blockIdx.z * cZ;

    const int cA = w * 64 + l;
    const unsigned short* gA0 = A + (size_t)(row0 + (cA >> 2)) * lda + (cA & 3) * 8;
    const unsigned short* gB0 = Bt + (size_t)(col0 + (cA >> 2)) * ldb + (cA & 3) * 8;
    unsigned short* lA0 = &As[w * 512];
    unsigned short* lB0 = &Bs[w * 512];
    const unsigned short* gB1 = nullptr;
    unsigned short* lB1 = nullptr;
    if constexpr (BN == 128) {
        gB1 = Bt + (size_t)(col0 + 64 + (cA >> 2)) * ldb + (cA & 3) * 8;
        lB1 = &Bs[2048 + w * 512];
    }
    const unsigned short* gA1 = nullptr;
    unsigned short* lA1 = nullptr;
    if constexpr (TM == 128) {
        gA1 = A + (size_t)(row0 + 64 + (cA >> 2)) * lda + (cA & 3) * 8;
        lA1 = &As[2048 + w * 512];
    }

    const int wr = (BN == 128) ? (w >> 1) * (TM / 2) : w * (TM / 4);
    const int wc = (BN == 128) ? (w & 1) * 64 : 0;
    const int lr = l & 15, lk = (l >> 4) * 8;
    const int aBase = (wr + lr) * 32 + lk;
    const int bBase = (wc + lr) * 32 + lk;

    f32x4 acc[M_REP][4] = {};

    for (int k0 = 0; k0 < K; k0 += 32) {
        glds16(gA0, lA0);  gA0 += 32;
        if constexpr (TM == 128) { glds16(gA1, lA1); gA1 += 32; }
        glds16(gB0, lB0);  gB0 += 32;
        if constexpr (BN == 128) { glds16(gB1, lB1); gB1 += 32; }
        __syncthreads();
        bf16x8 af[M_REP], bfr[4];
        #pragma unroll
        for (int m = 0; m < M_REP; m++)
            af[m] = *reinterpret_cast<const bf16x8*>(&As[aBase + m * 512]);
        #pragma unroll
        for (int n = 0; n < 4; n++)
            bfr[n] = *reinterpret_cast<const bf16x8*>(&Bs[bBase + n * 512]);
        #pragma unroll
        for (int m = 0; m < M_REP; m++)
            #pragma unroll
            for (int n = 0; n < 4; n++)
                acc[m][n] = __builtin_amdgcn_mfma_f32_16x16x32_bf16(
                    af[m], bfr[n], acc[m][n], 0, 0, 0);
        __syncthreads();
    }

    const int r0 = row0 + wr + (l >> 4) * 4;
    const int c0 = col0 + wc + lr;
    float bv[4] = {0.f, 0.f, 0.f, 0.f};
    if (BIAS) {
        #pragma unroll
        for (int n = 0; n < 4; n++) bv[n] = bias[c0 + n * 16];
    }
    #pragma unroll
    for (int m = 0; m < M_REP; m++) {
        #pragma unroll
        for (int j = 0; j < 4; j++) {
            const int row = r0 + m * 16 + j;
            #pragma unroll
            for (int n = 0; n < 4; n++) {
                float v = acc[m][n][j];
                if (BIAS) v += bv[n];
                if (ACT == 1) v = tanhf(v);
                if (ACT == 2) v = 0.5f * v * (1.f + erff(v * 0.70710678118f));
                if (RES) v += res[(size_t)row * ldr + c0 + n * 16];
                if (OBF) Cb[(size_t)row * ldc + c0 + n * 16] = f2bf(v);
                else     Cf[(size_t)row * ldc + c0 + n * 16] = v;
            }
        }
    }
}

// ======================= megapack: all weight preprocessing =======================
__device__ __forceinline__ void packT_body(float* sm, const float* __restrict__ in,
                                           unsigned short* __restrict__ out,
                                           int K, int N, int bx, int by)
{
    float (*t)[33] = (float(*)[33])sm;
    const int k0 = bx * 32, n0 = by * 32;
    const int tx = threadIdx.x & 31, ty = threadIdx.x >> 5;
    #pragma unroll
    for (int i = 0; i < 4; i++)
        t[ty + i * 8][tx] = in[(size_t)(k0 + ty + i * 8) * N + n0 + tx];
    __syncthreads();
    #pragma unroll
    for (int i = 0; i < 4; i++)
        out[(size_t)(n0 + ty + i * 8) * K + k0 + tx] = f2bf(t[tx][ty + i * 8]);
}

__device__ __forceinline__ void cast_body(const float* __restrict__ in,
                                          unsigned short* __restrict__ out, int blk)
{
    const long i = ((long)blk * 256 + threadIdx.x) * 8;
    float4 a = *(const float4*)(in + i);
    float4 b = *(const float4*)(in + i + 4);
    u16x8 o;
    o[0] = f2bf(a.x); o[1] = f2bf(a.y); o[2] = f2bf(a.z); o[3] = f2bf(a.w);
    o[4] = f2bf(b.x); o[5] = f2bf(b.y); o[6] = f2bf(b.z); o[7] = f2bf(b.w);
    *reinterpret_cast<u16x8*>(out + i) = o;
}

__global__ __launch_bounds__(256)
void megapack(const float* __restrict__ qkv_w, const float* __restrict__ gate_w,
              const float* __restrict__ mlp_w1, const float* __restrict__ mlp_w2,
              const float* __restrict__ hash_proj, const float* __restrict__ head_w,
              const float* __restrict__ enc_w, const float* __restrict__ dec_w,
              const float* __restrict__ byte_emb,
              const float* __restrict__ qkv_b, const float* __restrict__ gate_b,
              const float* __restrict__ dec_b, const float* __restrict__ head_b,
              unsigned short* __restrict__ wcat, unsigned short* __restrict__ w1T,
              unsigned short* __restrict__ w2T, unsigned short* __restrict__ whashT,
              unsigned short* __restrict__ hwT, unsigned short* __restrict__ encT,
              unsigned short* __restrict__ decb, unsigned short* __restrict__ embB,
              float* __restrict__ cbias, float* __restrict__ fb)
{
    __shared__ float sm[32 * 33];
    int id = blockIdx.x;
    if (id < 3072) {                 // qkv_w: z4, K512, N1536 (16x48)
        int z = id / 768, r = id % 768;
        packT_body(sm, qkv_w + (size_t)z * 512 * 1536, wcat + (size_t)z * 2048 * 512,
                   512, 1536, r % 16, r / 16);
    } else if (id < 4096) {          // gate_w: z4, K512, N512 (16x16)
        id -= 3072; int z = id / 256, r = id % 256;
        packT_body(sm, gate_w + (size_t)z * 512 * 512,
                   wcat + (size_t)z * 2048 * 512 + (size_t)1536 * 512,
                   512, 512, r % 16, r / 16);
    } else if (id < 8192) {          // mlp_w1: z4, K512, N2048 (16x64)
        id -= 4096; int z = id / 1024, r = id % 1024;
        packT_body(sm, mlp_w1 + (size_t)z * 512 * 2048, w1T + (size_t)z * 2048 * 512,
                   512, 2048, r % 16, r / 16);
    } else if (id < 12288) {         // mlp_w2: z4, K2048, N512 (64x16)
        id -= 8192; int z = id / 1024, r = id % 1024;
        packT_body(sm, mlp_w2 + (size_t)z * 2048 * 512, w2T + (size_t)z * 512 * 2048,
                   2048, 512, r % 64, r / 64);
    } else if (id < 12544) {         // hash_proj (16x16)
        id -= 12288;
        packT_body(sm, hash_proj, whashT, 512, 512, id % 16, id / 16);
    } else if (id < 12672) {         // head_w: K512, N256 (16x8)
        id -= 12544;
        packT_body(sm, head_w, hwT, 512, 256, id % 16, id / 16);
    } else if (id < 14720) {         // enc_w: z8, K512, N512 (16x16)
        id -= 12672; int z = id / 256, r = id % 256;
        packT_body(sm, enc_w + (size_t)z * 512 * 512, encT + (size_t)z * 512 * 512,
                   512, 512, r % 16, r / 16);
    } else if (id < 15744) {         // dec_w cast: 2097152 elems
        cast_body(dec_w, decb, id - 14720);
    } else if (id < 15808) {         // byte_emb cast: 131072 elems
        cast_body(byte_emb, embB, id - 15744);
    } else if (id < 15840) {         // catbias: 32 blocks
        id -= 15808;
        const int i = id >> 3;
        const int n = (id & 7) * 256 + threadIdx.x;
        cbias[i * 2048 + n] = (n < 1536) ? qkv_b[i * 1536 + n] : gate_b[i * 512 + n - 1536];
    } else {                         // fused decoder+head bias (1 block)
        const int o = threadIdx.x;
        float s = head_b[o];
        for (int d = 0; d < DIMD; d++) s = fmaf(dec_b[d], head_w[d * 256 + o], s);
        #pragma unroll
        for (int p = 0; p < PP; p++) fb[p * 256 + o] = s;
    }
}

// ---- LayerNorm (ln1): one wave per row, bf16 out ----
__global__ __launch_bounds__(256)
void ln_kernel(const float* __restrict__ x, const float* __restrict__ g,
               const float* __restrict__ b, unsigned short* __restrict__ h)
{
    const int row = blockIdx.x * 4 + (threadIdx.x >> 6);
    const int lane = threadIdx.x & 63;
    const float* xr = x + (long)row * DIMD;
    float4 v0 = *(const float4*)(xr + lane * 8);
    float4 v1 = *(const float4*)(xr + lane * 8 + 4);
    float xv[8] = {v0.x, v0.y, v0.z, v0.w, v1.x, v1.y, v1.z, v1.w};
    float s = 0.f, q = 0.f;
    #pragma unroll
    for (int j = 0; j < 8; j++) { s += xv[j]; q += xv[j] * xv[j]; }
    #pragma unroll
    for (int off = 1; off < 64; off <<= 1) {
        s += __shfl_xor(s, off);
        q += __shfl_xor(q, off);
    }
    const float mean = s * (1.f / DIMD);
    const float var  = q * (1.f / DIMD) - mean * mean;
    const float rstd = rsqrtf(var + 1e-5f);
    float4 g0 = *(const float4*)(g + lane * 8);
    float4 g1 = *(const float4*)(g + lane * 8 + 4);
    float4 b0 = *(const float4*)(b + lane * 8);
    float4 b1 = *(const float4*)(b + lane * 8 + 4);
    float gv[8] = {g0.x, g0.y, g0.z, g0.w, g1.x, g1.y, g1.z, g1.w};
    float bb[8] = {b0.x, b0.y, b0.z, b0.w, b1.x, b1.y, b1.z, b1.w};
    u16x8 o;
    #pragma unroll
    for (int j = 0; j < 8; j++) o[j] = f2bf((xv[j] - mean) * rstd * gv[j] + bb[j]);
    *reinterpret_cast<u16x8*>(h + (long)row * DIMD + lane * 8) = o;
}

// ---- fused embed+encode ----
__global__ __launch_bounds__(128)
void embed_kernel(const int* __restrict__ bytes, const float* __restrict__ E,
                  const float* __restrict__ enc_b, float* __restrict__ x0,
                  unsigned short* __restrict__ x0b)
{
    const int patch = blockIdx.x;
    __shared__ int by[PP];
    if (threadIdx.x < PP) by[threadIdx.x] = bytes[patch * PP + threadIdx.x];
    __syncthreads();
    const int o = threadIdx.x * 4;
    float4 acc = *(const float4*)(enc_b + o);
    #pragma unroll
    for (int p = 0; p < PP; p++) {
        float4 e = *(const float4*)(E + ((long)(p * 256 + by[p])) * DIMD + o);
        acc.x += e.x; acc.y += e.y; acc.z += e.z; acc.w += e.w;
    }
    *(float4*)(x0 + (long)patch * DIMD + o) = acc;
    u16x4 ob; ob[0] = f2bf(acc.x); ob[1] = f2bf(acc.y);
    ob[2] = f2bf(acc.z); ob[3] = f2bf(acc.w);
    *reinterpret_cast<u16x4*>(x0b + (long)patch * DIMD + o) = ob;
}

// ---- scan partial sums: 256 thr, 2 dims/thread, ushort2 loads ----
__global__ __launch_bounds__(256)
void scan_partial(const unsigned short* __restrict__ qg, float* __restrict__ S)
{
    const int b = blockIdx.x >> 6, c = blockIdx.x & 63, d2 = threadIdx.x * 2;
    const unsigned short* base = qg + (size_t)(b * LPATCH + c * CLEN) * QGS;
    float s0 = 0.f, s1 = 0.f;
    for (int l = 0; l < CLEN; l++) {
        ushort2 kk = *(const ushort2*)(base + l * QGS + DIMD + d2);
        ushort2 vv = *(const ushort2*)(base + l * QGS + 2 * DIMD + d2);
        s0 = fmaf(bf2f(kk.x), bf2f(vv.x), s0);
        s1 = fmaf(bf2f(kk.y), bf2f(vv.y), s1);
    }
    *(float2*)(S + (size_t)(b * NCHUNK + c) * DIMD + d2) = make_float2(s0, s1);
}

// ---- exclusive prefix over chunk sums: register-batched loads ----
__global__ __launch_bounds__(128)
void scan_prefix(float* __restrict__ S)
{
    const int b = blockIdx.x & 3;
    const int d = (blockIdx.x >> 2) * 128 + threadIdx.x;
    float* Sp = S + (size_t)b * NCHUNK * DIMD + d;
    float v[NCHUNK];
    #pragma unroll
    for (int c = 0; c < NCHUNK; c++) v[c] = Sp[(size_t)c * DIMD];
    float run = 0.f;
    #pragma unroll
    for (int c = 0; c < NCHUNK; c++) {
        Sp[(size_t)c * DIMD] = run;
        run += v[c];
    }
}

// ---- fused scan apply + residual + LN2 (barrier-free, K8/K14-proven) ----
__global__ __launch_bounds__(512)
void scan_apply_ln(const unsigned short* __restrict__ qg,
                   const float* __restrict__ S, float* __restrict__ x,
                   const float* __restrict__ lg, const float* __restrict__ lb,
                   unsigned short* __restrict__ h)
{
    const int b = blockIdx.x >> 6, c = blockIdx.x & 63;
    const int w = threadIdx.x >> 6, lane = threadIdx.x & 63;
    const int d0 = lane * 8;

    float kv[8];
    {
        const float* Sp = S + (size_t)(b * NCHUNK + c) * DIMD + d0;
        float4 a = *(const float4*)Sp;
        float4 bq = *(const float4*)(Sp + 4);
        kv[0] = a.x; kv[1] = a.y; kv[2] = a.z; kv[3] = a.w;
        kv[4] = bq.x; kv[5] = bq.y; kv[6] = bq.z; kv[7] = bq.w;
    }
    const int row0 = b * LPATCH + c * CLEN;
    for (int l = 0; l < 2 * w; l++) {
        const unsigned short* qb = qg + (size_t)(row0 + l) * QGS;
        u16x8 kk = *reinterpret_cast<const u16x8*>(qb + DIMD + d0);
        u16x8 vv = *reinterpret_cast<const u16x8*>(qb + 2 * DIMD + d0);
        #pragma unroll
        for (int j = 0; j < 8; j++) kv[j] = fmaf(bf2f(kk[j]), bf2f(vv[j]), kv[j]);
    }

    float gv[8], bv[8];
    {
        float4 g0 = *(const float4*)(lg + d0);
        float4 g1 = *(const float4*)(lg + d0 + 4);
        float4 b0 = *(const float4*)(lb + d0);
        float4 b1 = *(const float4*)(lb + d0 + 4);
        gv[0] = g0.x; gv[1] = g0.y; gv[2] = g0.z; gv[3] = g0.w;
        gv[4] = g1.x; gv[5] = g1.y; gv[6] = g1.z; gv[7] = g1.w;
        bv[0] = b0.x; bv[1] = b0.y; bv[2] = b0.z; bv[3] = b0.w;
        bv[4] = b1.x; bv[5] = b1.y; bv[6] = b1.z; bv[7] = b1.w;
    }

    for (int l = 2 * w; l < 2 * w + 2; l++) {
        const unsigned short* qb = qg + (size_t)(row0 + l) * QGS;
        u16x8 qq = *reinterpret_cast<const u16x8*>(qb + d0);
        u16x8 kk = *reinterpret_cast<const u16x8*>(qb + DIMD + d0);
        u16x8 vv = *reinterpret_cast<const u16x8*>(qb + 2 * DIMD + d0);
        u16x8 gg = *reinterpret_cast<const u16x8*>(qb + 3 * DIMD + d0);
        float* xr = x + (size_t)(row0 + l) * DIMD + d0;
        float4 xv0 = *(const float4*)xr;
        float4 xv1 = *(const float4*)(xr + 4);
        float xold[8] = {xv0.x, xv0.y, xv0.z, xv0.w, xv1.x, xv1.y, xv1.z, xv1.w};
        float xn[8];
        float s = 0.f, qs = 0.f;
        #pragma unroll
        for (int j = 0; j < 8; j++) {
            kv[j] = fmaf(bf2f(kk[j]), bf2f(vv[j]), kv[j]);
            const float sg = 1.f / (1.f + expf(-bf2f(gg[j])));
            const float nv = xold[j] + bf2f(qq[j]) * kv[j] * sg;
            xn[j] = nv; s += nv; qs += nv * nv;
        }
        *(float4*)xr       = make_float4(xn[0], xn[1], xn[2], xn[3]);
        *(float4*)(xr + 4) = make_float4(xn[4], xn[5], xn[6], xn[7]);
        #pragma unroll
        for (int off = 1; off < 64; off <<= 1) {
            s += __shfl_xor(s, off);
            qs += __shfl_xor(qs, off);
        }
        const float mean = s * (1.f / DIMD);
        const float var  = qs * (1.f / DIMD) - mean * mean;
        const float rstd = rsqrtf(var + 1e-5f);
        u16x8 ho;
        #pragma unroll
        for (int j = 0; j < 8; j++) ho[j] = f2bf((xn[j] - mean) * rstd * gv[j] + bv[j]);
        *reinterpret_cast<u16x8*>(h + (size_t)(row0 + l) * DIMD + d0) = ho;
    }
}

extern "C" void kernel_launch(void* const* d_in, const int* in_sizes, int n_in,
                              void* d_out, int out_size, void* d_ws, size_t ws_size,
                              hipStream_t stream)
{
    (void)in_sizes; (void)n_in; (void)out_size; (void)ws_size;

    const int*   bytes_in  = (const int*)d_in[0];
    const float* byte_emb  = (const float*)d_in[1];
    const float* enc_w     = (const float*)d_in[2];
    const float* enc_b     = (const float*)d_in[3];
    const float* hash_proj = (const float*)d_in[4];
    const float* qkv_w     = (const float*)d_in[5];
    const float* qkv_b     = (const float*)d_in[6];
    const float* gate_w    = (const float*)d_in[7];
    const float* gate_b    = (const float*)d_in[8];
    const float* ln1_g     = (const float*)d_in[9];
    const float* ln1_b     = (const float*)d_in[10];
    const float* mlp_w1    = (const float*)d_in[11];
    const float* mlp_b1    = (const float*)d_in[12];
    const float* mlp_w2    = (const float*)d_in[13];
    const float* mlp_b2    = (const float*)d_in[14];
    const float* ln2_g     = (const float*)d_in[15];
    const float* ln2_b     = (const float*)d_in[16];
    const float* dec_w     = (const float*)d_in[17];
    const float* dec_b     = (const float*)d_in[18];
    const float* head_w    = (const float*)d_in[19];
    const float* head_b    = (const float*)d_in[20];
    float* out = (float*)d_out;

    // ---- workspace layout ----
    char* ws = (char*)d_ws;
    size_t o = 0;
    auto alloc = [&](size_t bytes) { char* p = ws + o; o += (bytes + 255) & ~(size_t)255; return p; };
    unsigned short* wcat   = (unsigned short*)alloc((size_t)4 * 2048 * 512 * 2);
    unsigned short* w1T    = (unsigned short*)alloc((size_t)4 * 2048 * 512 * 2);
    unsigned short* w2T    = (unsigned short*)alloc((size_t)4 * 512 * 2048 * 2);
    unsigned short* whashT = (unsigned short*)alloc((size_t)512 * 512 * 2);
    unsigned short* wWfT   = (unsigned short*)alloc((size_t)2048 * 512 * 2);
    unsigned short* encT   = (unsigned short*)alloc((size_t)8 * 512 * 512 * 2);
    unsigned short* hwT    = (unsigned short*)alloc((size_t)256 * 512 * 2);
    unsigned short* decb   = (unsigned short*)alloc((size_t)512 * 8 * 512 * 2);
    unsigned short* embB   = (unsigned short*)alloc((size_t)256 * 512 * 2);
    float* cbias           = (float*)alloc((size_t)4 * 2048 * 4);
    float* fb              = (float*)alloc(2048 * 4);
    float* E               = (float*)alloc((size_t)8 * 256 * 512 * 4);
    float* x               = (float*)alloc((size_t)MROWS * DIMD * 4);
    float* x0              = (float*)alloc((size_t)MROWS * DIMD * 4);
    unsigned short* x0b    = (unsigned short*)alloc((size_t)MROWS * DIMD * 2);
    unsigned short* h      = (unsigned short*)alloc((size_t)MROWS * DIMD * 2);
    unsigned short* xb     = (unsigned short*)alloc((size_t)MROWS * DIMD * 2);
    float* S               = (float*)alloc((size_t)BBATCH * NCHUNK * DIMD * 4);
    unsigned short* qg     = (unsigned short*)alloc((size_t)MROWS * 2048 * 2);
    unsigned short* hid    = (unsigned short*)alloc((size_t)MROWS * 2048 * 2);

    // ---- 1. all weight preprocessing (incl. fused decoder+head bias) ----
    megapack<<<dim3(15841), 256, 0, stream>>>(
        qkv_w, gate_w, mlp_w1, mlp_w2, hash_proj, head_w, enc_w, dec_w, byte_emb,
        qkv_b, gate_b, dec_b, head_b,
        wcat, w1T, w2T, whashT, hwT, encT, decb, embB, cbias, fb);

    // ---- 2. WfT[p*256+o][d] = sum_c head_wT[o][c] * dec_w[d][p][c] ----
    mfma_gemm<64, 64, 0, false, false, true><<<dim3(4, 8, 8), 256, 0, stream>>>(
        hwT, 512, 0L, decb, PP * 512, 512L,
        nullptr, nullptr, 0, wWfT, 512, (long)256 * 512, 512);

    // ---- 3. E[p] = byte_emb @ enc_w[p] ----
    mfma_gemm<64, 64, 0, false, false, false><<<dim3(4, 8, 8), 256, 0, stream>>>(
        embB, 512, 0L, encT, 512, (long)512 * 512,
        nullptr, nullptr, 0, E, 512, (long)256 * 512, 512);

    embed_kernel<<<dim3(MROWS), dim3(128), 0, stream>>>(bytes_in, E, enc_b, x0, x0b);

    // ---- 4. x = x0 + tanh(x0 @ hash_proj) ----
    mfma_gemm<64, 64, 1, false, true, false><<<dim3(MROWS / 64, 8, 1), 256, 0, stream>>>(
        x0b, DIMD, 0L, whashT, DIMD, 0L, nullptr, x0, DIMD, x, DIMD, 0L, DIMD);

    for (int i = 0; i < NLAYER; i++) {
        ln_kernel<<<dim3(MROWS / 4), 256, 0, stream>>>(x, ln1_g + i * DIMD, ln1_b + i * DIMD, h);
        mfma_gemm<64, 128, 0, true, false, true><<<dim3(MROWS / 64, 16, 1), 256, 0, stream>>>(
            h, DIMD, 0L, wcat + (size_t)i * 2048 * 512, DIMD, 0L,
            cbias + (size_t)i * 2048, nullptr, 0, qg, 2048, 0L, DIMD);
        scan_partial<<<dim3(BBATCH * NCHUNK), 256, 0, stream>>>(qg, S);
        scan_prefix<<<dim3(16), dim3(128), 0, stream>>>(S);
        scan_apply_ln<<<dim3(BBATCH * NCHUNK), dim3(512), 0, stream>>>(
            qg, S, x, ln2_g + i * DIMD, ln2_b + i * DIMD, h);
        mfma_gemm<64, 128, 2, true, false, true><<<dim3(MROWS / 64, 16, 1), 256, 0, stream>>>(
            h, DIMD, 0L, w1T + (size_t)i * 2048 * 512, DIMD, 0L,
            mlp_b1 + (size_t)i * 2048, nullptr, 0, hid, 2048, 0L, DIMD);
        if (i < NLAYER - 1) {
            mfma_gemm<64, 64, 0, true, true, false><<<dim3(MROWS / 64, 8, 1), 256, 0, stream>>>(
                hid, 2048, 0L, w2T + (size_t)i * 512 * 2048, 2048, 0L,
                mlp_b2 + (size_t)i * DIMD, x, DIMD, x, DIMD, 0L, 2048);
        } else {
            mfma_gemm<64, 64, 0, true, true, true><<<dim3(MROWS / 64, 8, 1), 256, 0, stream>>>(
                hid, 2048, 0L, w2T + (size_t)i * 512 * 2048, 2048, 0L,
                mlp_b2 + (size_t)i * DIMD, x, DIMD, xb, DIMD, 0L, 2048);
        }
    }

    // ---- head ----
    mfma_gemm<64, 128, 0, true, false, false><<<dim3(MROWS / 64, 16, 1), 256, 0, stream>>>(
        xb, DIMD, 0L, wWfT, DIMD, 0L, fb, nullptr, 0, out, 2048, 0L, DIMD);
}